// Round 11
// baseline (513.791 us; speedup 1.0000x reference)
//
#include <hip/hip_runtime.h>
#include <hip/hip_bf16.h>
#include <math.h>

// ---- problem constants ----
static constexpr int LEN = 4096;   // H*W
static constexpr int HN  = 64;     // H
static constexpr int WN  = 64;     // W
static constexpr int NB  = 2;      // batch
static constexpr int DM  = 192;    // d_model
static constexpr int DIM = 384;    // d_inner
static constexpr int NST = 16;     // n_state
static constexpr int DTR = 12;     // dt_rank
static constexpr int KD  = 4;      // directions
static constexpr int NC  = 64;     // scan chunks
static constexpr int CHL = LEN / NC; // 64 elements per chunk

// direction k seq-position -> pixel row index (uniform across a wave)
__device__ __forceinline__ int maprow(int k, int gl) {
    int g = (k & 2) ? (LEN - 1 - gl) : gl;
    return (k & 1) ? (((g & 63) << 6) | (g >> 6)) : g;
}

// ---------------------------------------------------------------------------
// weight transform: w (co,ci,3,3) -> wt (t, co, ci)   [ci contiguous]
__global__ void k_wtr(const float* __restrict__ w, float* __restrict__ wt,
                      int cin, int cout, int n)
{
    int idx = blockIdx.x * 256 + threadIdx.x;
    if (idx >= n) return;
    int ci = idx % cin; int r = idx / cin;
    int co = r % cout; int t = r / cout;
    wt[idx] = w[((size_t)(co * cin + ci)) * 9 + t];
}

// pad x_proj_w (4,44,384) -> WX (192,384), rows k*48+c (c<44), zero pad
__global__ void k_wxp(const float* __restrict__ xpw, float* __restrict__ WX)
{
    int idx = blockIdx.x * 256 + threadIdx.x;    // 192*384
    if (idx >= 192 * DIM) return;
    int row = idx / DIM, d = idx - row * DIM;
    int k = row / 48, c = row - k * 48;
    WX[idx] = (c < 44) ? xpw[((size_t)(k * 44 + c)) * DIM + d] : 0.f;
}

// ---------------------------------------------------------------------------
// x (B,64,L) planar -> FN NHWC cols [0,64)
__global__ void k_tr_in(const float* __restrict__ x, float* __restrict__ FN)
{
    __shared__ float t[64][65];
    int b = blockIdx.y, r = blockIdx.x;
    int tid = threadIdx.x;
#pragma unroll
    for (int i = 0; i < 16; ++i) {
        int idx = (i << 8) + tid;
        int c = idx >> 6, xc = idx & 63;
        t[c][xc] = x[((size_t)(b * 64 + c)) * LEN + r * WN + xc];
    }
    __syncthreads();
#pragma unroll
    for (int i = 0; i < 16; ++i) {
        int idx = (i << 8) + tid;
        int px = idx >> 6, c = idx & 63;
        FN[((size_t)(b * LEN + r * WN + px)) * DM + c] = t[c][px];
    }
}

// ---------------------------------------------------------------------------
// implicit-GEMM conv3x3, dy-split partials. tile 64px x 32oc.
// halo-staged As; Bs transposed [dx][oc][ci]; all LDS reads ds_read_b128.
template<int PLANAR>
__global__ void __launch_bounds__(256) k_convg(
    const float* __restrict__ in, int cbuf, int cin, int cout,
    const float* __restrict__ wt,
    float* __restrict__ part)
{
    __shared__ float As[66][36];
    __shared__ float Bs[3][32][36];
    int zz = blockIdx.z;
    int b = zz / 3, s = zz % 3;
    int y0 = blockIdx.x;
    int n0 = blockIdx.y << 5;
    int tid = threadIdx.x;
    int tl = tid & 15, tn = (tid >> 4) << 1;
    int y = y0 + s - 1;
    bool yok = (unsigned)y < (unsigned)HN;
    const float* inb = in + ((size_t)b * LEN + (size_t)y * WN) * cbuf;
    float acc[4][2] = {};

    for (int ci0 = 0; ci0 < cin; ci0 += 32) {
        // stage As[px][ci']: px in [0,66) maps to x = px-1 (halo)
#pragma unroll
        for (int it = 0; it < 3; ++it) {
            int fi = (it << 8) + tid;
            if (fi < 528) {                       // 66 rows x 8 quads
                int px = fi >> 3, ci4 = (fi & 7) << 2;
                int xx = px - 1;
                float4 v = make_float4(0.f, 0.f, 0.f, 0.f);
                if (yok && (unsigned)xx < (unsigned)WN)
                    v = *(const float4*)(inb + (size_t)xx * cbuf + ci0 + ci4);
                *(float4*)(&As[px][ci4]) = v;
            }
        }
        // stage Bs[dx][oc][ci'] for all 3 dx taps (wt is (t, co, ci))
#pragma unroll
        for (int dx = 0; dx < 3; ++dx) {
            int oc = tid >> 3, ci4 = (tid & 7) << 2;
            int t = s * 3 + dx;
            float4 wv = *(const float4*)(wt + ((size_t)(t * cout + n0 + oc)) * cin + ci0 + ci4);
            *(float4*)(&Bs[dx][oc][ci4]) = wv;
        }
        __syncthreads();
#pragma unroll
        for (int dx = 0; dx < 3; ++dx) {
#pragma unroll
            for (int k = 0; k < 32; k += 4) {
                float4 b0 = *(const float4*)(&Bs[dx][tn][k]);
                float4 b1 = *(const float4*)(&Bs[dx][tn + 1][k]);
#pragma unroll
                for (int i = 0; i < 4; ++i) {
                    float4 a = *(const float4*)(&As[tl + (i << 4) + dx][k]);
                    acc[i][0] += a.x * b0.x + a.y * b0.y + a.z * b0.z + a.w * b0.w;
                    acc[i][1] += a.x * b1.x + a.y * b1.y + a.z * b1.z + a.w * b1.w;
                }
            }
        }
        __syncthreads();
    }
    if (PLANAR) {
#pragma unroll
        for (int j = 0; j < 2; ++j) {
            float* pp = part + ((size_t)((s * NB + b) * 64 + n0 + tn + j)) * LEN + y0 * WN + tl;
#pragma unroll
            for (int i = 0; i < 4; ++i) pp[i << 4] = acc[i][j];
        }
    } else {
#pragma unroll
        for (int i = 0; i < 4; ++i) {
            float* pp = part + (((size_t)(s * NB + b) * LEN) + y0 * WN + tl + (i << 4)) * 32 + tn;
            pp[0] = acc[i][0]; pp[1] = acc[i][1];
        }
    }
}

// epilogue: sum 3 dy-partials + bias + leakyrelu -> FN NHWC col block
__global__ void k_ep_nhwc(const float* __restrict__ part, const float* __restrict__ bias,
                          float* __restrict__ FN, int co0, float slope)
{
    int idx = blockIdx.x * 256 + threadIdx.x;
    int co = idx & 31, px = idx >> 5;
    const size_t S = (size_t)NB * LEN * 32;
    float v = part[idx] + part[S + idx] + part[2 * S + idx] + bias[co];
    v = v > 0.f ? v : v * slope;
    FN[(size_t)px * DM + co0 + co] = v;
}

// epilogue: sum 3 dy-partials + bias -> planar out (B,64,L)
__global__ void k_ep_pl(const float* __restrict__ part, const float* __restrict__ bias,
                        float* __restrict__ out)
{
    int idx = blockIdx.x * 256 + threadIdx.x;
    int oc = (idx >> 12) & 63;
    const size_t S = (size_t)NB * 64 * LEN;
    float v = part[idx] + part[S + idx] + part[2 * S + idx] + bias[oc];
    out[idx] = v;
}

// ---------------------------------------------------------------------------
// LayerNorm over 192 channels, NHWC in/out
__global__ void k_ln(const float* __restrict__ FN, const float* __restrict__ g,
                     const float* __restrict__ be, float* __restrict__ xn)
{
    int lane = threadIdx.x & 63;
    int pix  = (blockIdx.x << 2) + (threadIdx.x >> 6);
    const float* fp = FN + (size_t)pix * DM;
    float v0 = fp[lane];
    float v1 = fp[lane + 64];
    float v2 = fp[lane + 128];
    float s = v0 + v1 + v2, ss = v0 * v0 + v1 * v1 + v2 * v2;
#pragma unroll
    for (int off = 1; off < 64; off <<= 1) { s += __shfl_xor(s, off); ss += __shfl_xor(ss, off); }
    float mu = s * (1.f / 192.f);
    float var = ss * (1.f / 192.f) - mu * mu;
    float rstd = rsqrtf(var + 1e-5f);
    float* op = xn + (size_t)pix * DM;
    op[lane]       = (v0 - mu) * rstd * g[lane]       + be[lane];
    op[lane + 64]  = (v1 - mu) * rstd * g[lane + 64]  + be[lane + 64];
    op[lane + 128] = (v2 - mu) * rstd * g[lane + 128] + be[lane + 128];
}

// ---------------------------------------------------------------------------
// tiled f32 GEMM: A (B*L, K) NHWC x Wt (N, K) -> planar (B,outC,L) or NHWC.
// b128 LDS reads; micro-tile rows tl+16i (2-way bank aliasing only).
__global__ void __launch_bounds__(256) k_gemm(
    const float* __restrict__ A, int K,
    const float* __restrict__ Wt,
    const float* __restrict__ res,
    float* __restrict__ Cp, int outC, int nhwc)
{
    __shared__ float As[64][68];
    __shared__ float Bs[64][68];
    int b  = blockIdx.z;
    int l0 = blockIdx.x << 6, n0 = blockIdx.y << 6;
    int tid = threadIdx.x;
    int tl = tid & 15, tn = (tid >> 4) << 2;
    float acc[4][4] = {};

    for (int k0 = 0; k0 < K; k0 += 64) {
#pragma unroll
        for (int s = 0; s < 4; ++s) {
            int e = (s << 10) + (tid << 2);
            int row = e >> 6, col = e & 63;
            float4 av = *(const float4*)(A + ((size_t)b * LEN + l0 + row) * K + k0 + col);
            *(float4*)(&As[row][col]) = av;
            float4 wv = *(const float4*)(Wt + (size_t)(n0 + row) * K + k0 + col);
            *(float4*)(&Bs[row][col]) = wv;
        }
        __syncthreads();
#pragma unroll
        for (int kk = 0; kk < 64; kk += 4) {
            float4 bv[4];
#pragma unroll
            for (int j = 0; j < 4; ++j) bv[j] = *(const float4*)(&Bs[tn + j][kk]);
#pragma unroll
            for (int i = 0; i < 4; ++i) {
                float4 a = *(const float4*)(&As[tl + (i << 4)][kk]);
#pragma unroll
                for (int j = 0; j < 4; ++j)
                    acc[i][j] += a.x * bv[j].x + a.y * bv[j].y + a.z * bv[j].z + a.w * bv[j].w;
            }
        }
        __syncthreads();
    }
    if (!nhwc) {
#pragma unroll
        for (int j = 0; j < 4; ++j) {
            size_t o = ((size_t)(b * outC) + n0 + tn + j) * LEN + l0 + tl;
#pragma unroll
            for (int i = 0; i < 4; ++i) {
                float v = acc[i][j];
                if (res) v += res[o + (i << 4)];
                Cp[o + (i << 4)] = v;
            }
        }
    } else {
#pragma unroll
        for (int i = 0; i < 4; ++i) {
            size_t o = ((size_t)b * LEN + l0 + tl + (i << 4)) * outC + n0 + tn;
            float4 v;
            v.x = acc[i][0]; v.y = acc[i][1]; v.z = acc[i][2]; v.w = acc[i][3];
            if (res) {
                float4 r = *(const float4*)(res + o);
                v.x += r.x; v.y += r.y; v.z += r.z; v.w += r.w;
            }
            *(float4*)(Cp + o) = v;
        }
    }
}

// ---------------------------------------------------------------------------
// depthwise conv3x3 + SiLU : xp planar (B,384,L) -> unh NHWC (B*L, 384)
__global__ void __launch_bounds__(256) k_dw(
    const float* __restrict__ xp, const float* __restrict__ w,
    const float* __restrict__ bias, float* __restrict__ unh)
{
    __shared__ float t[64][65];
    int b = blockIdx.z, cg = blockIdx.y, r = blockIdx.x;
    int x = threadIdx.x & 63, cs = threadIdx.x >> 6;
#pragma unroll
    for (int i = 0; i < 16; ++i) {
        int c = cg * 64 + cs * 16 + i;
        const float* ip = xp + ((size_t)(b * DIM + c)) * LEN;
        const float* wp = w + c * 9;
        float acc = bias[c];
#pragma unroll
        for (int dy = 0; dy < 3; ++dy) {
            int ry = r + dy - 1;
            if ((unsigned)ry >= (unsigned)HN) continue;
#pragma unroll
            for (int dx = 0; dx < 3; ++dx) {
                int xx = x + dx - 1;
                if ((unsigned)xx >= (unsigned)WN) continue;
                acc += ip[ry * WN + xx] * wp[dy * 3 + dx];
            }
        }
        acc = acc / (1.f + __expf(-acc));
        t[x][cs * 16 + i] = acc;
    }
    __syncthreads();
    float* op = unh + ((size_t)b * LEN + r * 64) * DIM + cg * 64;
#pragma unroll
    for (int i = 0; i < 16; ++i) {
        int idx = (i << 8) + threadIdx.x;
        int px = idx >> 6, cc = idx & 63;
        op[(size_t)px * DIM + cc] = t[px][cc];
    }
}

// ---------------------------------------------------------------------------
// delta = softplus(dtb + CX[:, k*48+0..12] @ dtw[k]^T), pixel-order output
__global__ void __launch_bounds__(384) k_delta(
    const float* __restrict__ CX, const float* __restrict__ dtw,
    const float* __restrict__ dtb, float* __restrict__ dlt)
{
    __shared__ float cs[16][12];
    int b = blockIdx.z, k = blockIdx.y;
    int lp0 = blockIdx.x << 4;
    int tid = threadIdx.x;
    if (tid < 192) {
        int p = tid / 12, r = tid - p * 12;
        cs[p][r] = CX[((size_t)(b * LEN) + lp0 + p) * 192 + k * 48 + r];
    }
    __syncthreads();
    float wt[DTR];
    const float* wp = dtw + ((size_t)(k * DIM) + tid) * DTR;
#pragma unroll
    for (int r = 0; r < DTR; ++r) wt[r] = wp[r];
    float bv = dtb[k * DIM + tid];
    float* dbase = dlt + (((size_t)(b * LEN) + lp0) * KD + k) * DIM + tid;
#pragma unroll
    for (int p = 0; p < 16; ++p) {
        float s = bv;
#pragma unroll
        for (int r = 0; r < DTR; ++r) s += cs[p][r] * wt[r];
        s = (s > 20.f) ? s : __logf(1.f + __expf(s));
        dbase[(size_t)p * KD * DIM] = s;
    }
}

// ---------------------------------------------------------------------------
// chunked scan phase A. thread = d; 16 states in registers; B staged from CX.
// geometric-A fast path (runtime verified, exp fallback kept).
__global__ void __launch_bounds__(384) k_scan_a(
    const float* __restrict__ unh, const float* __restrict__ CX,
    const float* __restrict__ alog, const float* __restrict__ dlt,
    float* __restrict__ hf, float* __restrict__ pA)
{
    __shared__ float bs[CHL * 16];
    int b = blockIdx.z, k = blockIdx.y, c = blockIdx.x;
    int d = threadIdx.x;
    for (int i = threadIdx.x; i < CHL * 16; i += 384) {
        int l = i >> 4, n = i & 15;
        int row = maprow(k, c * CHL + l);
        bs[i] = CX[((size_t)(b * LEN) + row) * 192 + k * 48 + 12 + n];
    }
    __syncthreads();

    float A[16], h[16];
    const float* ap = alog + ((size_t)(k * DIM + d)) * NST;
#pragma unroll
    for (int q = 0; q < 4; ++q) {
        float4 av = *(const float4*)(ap + q * 4);
        A[q * 4]     = -__expf(av.x); A[q * 4 + 1] = -__expf(av.y);
        A[q * 4 + 2] = -__expf(av.z); A[q * 4 + 3] = -__expf(av.w);
    }
    bool geo = true;
#pragma unroll
    for (int n = 1; n < 16; ++n)
        geo = geo && (fabsf(A[n] - (n + 1) * A[0]) <= 1e-4f * (n + 1) * fabsf(A[0]));
#pragma unroll
    for (int n = 0; n < 16; ++n) h[n] = 0.f;

    const float* ub = unh + (size_t)b * LEN * DIM + d;
    const float* db = dlt + ((size_t)(b * LEN) * KD + k) * DIM + d;
    size_t base = (((size_t)((b * KD + k) * NC + c)) * NST) * DIM + d;

    float dv0[4], uu0[4], dv1[4], uu1[4];
#pragma unroll
    for (int j = 0; j < 4; ++j) {
        int row = maprow(k, c * CHL + j);
        dv0[j] = db[(size_t)row * KD * DIM];
        uu0[j] = ub[(size_t)row * DIM];
    }
    if (geo) {
        float A0 = A[0];
        float p0 = 1.f;
        for (int l0 = 0; l0 < CHL; l0 += 4) {
            if (l0 + 4 < CHL) {
#pragma unroll
                for (int j = 0; j < 4; ++j) {
                    int row = maprow(k, c * CHL + l0 + 4 + j);
                    dv1[j] = db[(size_t)row * KD * DIM];
                    uu1[j] = ub[(size_t)row * DIM];
                }
            }
#pragma unroll
            for (int j = 0; j < 4; ++j) {
                float du = dv0[j] * uu0[j];
                const float* bl = bs + (l0 + j) * 16;
                float qv = __expf(dv0[j] * A0);
                float pw = qv;
                h[0] = qv * h[0] + du * bl[0];
#pragma unroll
                for (int n = 1; n < 16; ++n) { pw *= qv; h[n] = pw * h[n] + du * bl[n]; }
                p0 *= qv;
            }
#pragma unroll
            for (int j = 0; j < 4; ++j) { dv0[j] = dv1[j]; uu0[j] = uu1[j]; }
        }
        float pw = 1.f;
#pragma unroll
        for (int n = 0; n < 16; ++n) {
            pw *= p0;
            hf[base + (size_t)n * DIM] = h[n];
            pA[base + (size_t)n * DIM] = pw;
        }
    } else {
        float p[16];
#pragma unroll
        for (int n = 0; n < 16; ++n) p[n] = 1.f;
        for (int l0 = 0; l0 < CHL; l0 += 4) {
            if (l0 + 4 < CHL) {
#pragma unroll
                for (int j = 0; j < 4; ++j) {
                    int row = maprow(k, c * CHL + l0 + 4 + j);
                    dv1[j] = db[(size_t)row * KD * DIM];
                    uu1[j] = ub[(size_t)row * DIM];
                }
            }
#pragma unroll
            for (int j = 0; j < 4; ++j) {
                float du = dv0[j] * uu0[j];
                const float* bl = bs + (l0 + j) * 16;
#pragma unroll
                for (int n = 0; n < 16; ++n) {
                    float dA = __expf(dv0[j] * A[n]);
                    h[n] = dA * h[n] + du * bl[n];
                    p[n] *= dA;
                }
            }
#pragma unroll
            for (int j = 0; j < 4; ++j) { dv0[j] = dv1[j]; uu0[j] = uu1[j]; }
        }
#pragma unroll
        for (int n = 0; n < 16; ++n) {
            hf[base + (size_t)n * DIM] = h[n];
            pA[base + (size_t)n * DIM] = p[n];
        }
    }
}

// phase B: serial carry combine over chunks; hf[c] overwritten with carry-IN.
__global__ void k_scan_b(float* __restrict__ hf, const float* __restrict__ pA)
{
    int s = blockIdx.x * 256 + threadIdx.x;          // NB*KD*NST*DIM = 49152
    int bk = s / (NST * DIM);
    int r  = s - bk * (NST * DIM);
    size_t base = (size_t)bk * NC * NST * DIM + r;
    const size_t cs = (size_t)NST * DIM;
    float car = 0.f;
#pragma unroll 8
    for (int c = 0; c < NC; ++c) {
        float hfc = hf[base + c * cs], pc = pA[base + c * cs];
        hf[base + c * cs] = car;
        car = pc * car + hfc;
    }
}

// phase C: re-run chunk from carry-in; geometric-A fast path; y pixel-order.
__global__ void __launch_bounds__(384) k_scan_c(
    const float* __restrict__ unh, const float* __restrict__ CX,
    const float* __restrict__ alog, const float* __restrict__ hf,
    float* __restrict__ dlt)
{
    __shared__ float bs[CHL * 32];
    int b = blockIdx.z, k = blockIdx.y, c = blockIdx.x;
    int d = threadIdx.x;
    for (int i = threadIdx.x; i < CHL * 32; i += 384) {
        int l = i >> 5, n = i & 31;
        int row = maprow(k, c * CHL + l);
        bs[i] = CX[((size_t)(b * LEN) + row) * 192 + k * 48 + 12 + n];
    }
    __syncthreads();

    float A[16], h[16];
    const float* ap = alog + ((size_t)(k * DIM + d)) * NST;
#pragma unroll
    for (int q = 0; q < 4; ++q) {
        float4 av = *(const float4*)(ap + q * 4);
        A[q * 4]     = -__expf(av.x); A[q * 4 + 1] = -__expf(av.y);
        A[q * 4 + 2] = -__expf(av.z); A[q * 4 + 3] = -__expf(av.w);
    }
    bool geo = true;
#pragma unroll
    for (int n = 1; n < 16; ++n)
        geo = geo && (fabsf(A[n] - (n + 1) * A[0]) <= 1e-4f * (n + 1) * fabsf(A[0]));
    size_t base = (((size_t)((b * KD + k) * NC + c)) * NST) * DIM + d;
#pragma unroll
    for (int n = 0; n < 16; ++n) h[n] = hf[base + (size_t)n * DIM];

    const float* ub = unh + (size_t)b * LEN * DIM + d;
    float* db = dlt + ((size_t)(b * LEN) * KD + k) * DIM + d;

    int rows0[4], rows1[4];
    float dv0[4], uu0[4], dv1[4], uu1[4];
#pragma unroll
    for (int j = 0; j < 4; ++j) {
        rows0[j] = maprow(k, c * CHL + j);
        dv0[j] = db[(size_t)rows0[j] * KD * DIM];
        uu0[j] = ub[(size_t)rows0[j] * DIM];
    }
    if (geo) {
        float A0 = A[0];
        for (int l0 = 0; l0 < CHL; l0 += 4) {
            if (l0 + 4 < CHL) {
#pragma unroll
                for (int j = 0; j < 4; ++j) {
                    rows1[j] = maprow(k, c * CHL + l0 + 4 + j);
                    dv1[j] = db[(size_t)rows1[j] * KD * DIM];
                    uu1[j] = ub[(size_t)rows1[j] * DIM];
                }
            }
            float ys[4];
#pragma unroll
            for (int j = 0; j < 4; ++j) {
                const float* bl = bs + (l0 + j) * 32;
                float du = dv0[j] * uu0[j];
                float qv = __expf(dv0[j] * A0);
                float pw = qv;
                h[0] = qv * h[0] + du * bl[0];
                float y = h[0] * bl[16];
#pragma unroll
                for (int n = 1; n < 16; ++n) {
                    pw *= qv;
                    h[n] = pw * h[n] + du * bl[n];
                    y += h[n] * bl[16 + n];
                }
                ys[j] = y;
            }
#pragma unroll
            for (int j = 0; j < 4; ++j) db[(size_t)rows0[j] * KD * DIM] = ys[j];
#pragma unroll
            for (int j = 0; j < 4; ++j) { rows0[j] = rows1[j]; dv0[j] = dv1[j]; uu0[j] = uu1[j]; }
        }
    } else {
        for (int l0 = 0; l0 < CHL; l0 += 4) {
            if (l0 + 4 < CHL) {
#pragma unroll
                for (int j = 0; j < 4; ++j) {
                    rows1[j] = maprow(k, c * CHL + l0 + 4 + j);
                    dv1[j] = db[(size_t)rows1[j] * KD * DIM];
                    uu1[j] = ub[(size_t)rows1[j] * DIM];
                }
            }
            float ys[4];
#pragma unroll
            for (int j = 0; j < 4; ++j) {
                const float* bl = bs + (l0 + j) * 32;
                float du = dv0[j] * uu0[j];
                float y = 0.f;
#pragma unroll
                for (int n = 0; n < 16; ++n) {
                    float dA = __expf(dv0[j] * A[n]);
                    h[n] = dA * h[n] + du * bl[n];
                    y += h[n] * bl[16 + n];
                }
                ys[j] = y;
            }
#pragma unroll
            for (int j = 0; j < 4; ++j) db[(size_t)rows0[j] * KD * DIM] = ys[j];
#pragma unroll
            for (int j = 0; j < 4; ++j) { rows0[j] = rows1[j]; dv0[j] = dv1[j]; uu0[j] = uu1[j]; }
        }
    }
}

// ---------------------------------------------------------------------------
// merge 4 directions + D*u + out-LN + silu(z) gate -> yg NHWC (in-place over unh)
__global__ void k_merge(const float* __restrict__ y4, const float* __restrict__ unh,
                        const float* __restrict__ Ds, const float* __restrict__ ong,
                        const float* __restrict__ onb, const float* __restrict__ zt,
                        float* __restrict__ yg)
{
    int lane = threadIdx.x & 63;
    int pix = (blockIdx.x << 2) + (threadIdx.x >> 6);
    const float* yp = y4 + (size_t)pix * KD * DIM;
    const float* up = unh + (size_t)pix * DIM;
    float v[6]; float s = 0.f, ss = 0.f;
#pragma unroll
    for (int j = 0; j < 6; ++j) {
        int d = lane + (j << 6);
        float y = yp[d] + yp[DIM + d] + yp[2 * DIM + d] + yp[3 * DIM + d];
        float dsum = Ds[d] + Ds[DIM + d] + Ds[2 * DIM + d] + Ds[3 * DIM + d];
        y += dsum * up[d];
        v[j] = y; s += y; ss += y * y;
    }
#pragma unroll
    for (int off = 1; off < 64; off <<= 1) { s += __shfl_xor(s, off); ss += __shfl_xor(ss, off); }
    float mu = s * (1.f / 384.f);
    float var = ss * (1.f / 384.f) - mu * mu;
    float rstd = rsqrtf(var + 1e-5f);
    const float* zp = zt + (size_t)pix * DIM;
    float* op = yg + (size_t)pix * DIM;
#pragma unroll
    for (int j = 0; j < 6; ++j) {
        int d = lane + (j << 6);
        float zz = zp[d];
        float gate = zz / (1.f + __expf(-zz));
        op[d] = ((v[j] - mu) * rstd * ong[d] + onb[d]) * gate;
    }
}

// ---------------------------------------------------------------------------
extern "C" void kernel_launch(void* const* d_in, const int* in_sizes, int n_in,
                              void* d_out, int out_size, void* d_ws, size_t ws_size,
                              hipStream_t stream)
{
    const float* x    = (const float*)d_in[0];
    const float* c1w  = (const float*)d_in[1];  const float* c1b = (const float*)d_in[2];
    const float* c2w  = (const float*)d_in[3];  const float* c2b = (const float*)d_in[4];
    const float* c3w  = (const float*)d_in[5];  const float* c3b = (const float*)d_in[6];
    const float* c4w  = (const float*)d_in[7];  const float* c4b = (const float*)d_in[8];
    const float* c5w  = (const float*)d_in[9];  const float* c5b = (const float*)d_in[10];
    const float* ln1g = (const float*)d_in[11]; const float* ln1b= (const float*)d_in[12];
    const float* ipw  = (const float*)d_in[13];
    const float* dww  = (const float*)d_in[14]; const float* dwb = (const float*)d_in[15];
    const float* xpw  = (const float*)d_in[16];
    const float* dtw  = (const float*)d_in[17]; const float* dtb = (const float*)d_in[18];
    const float* alog = (const float*)d_in[19]; const float* dsv = (const float*)d_in[20];
    const float* ong  = (const float*)d_in[21]; const float* onb = (const float*)d_in[22];
    const float* opw  = (const float*)d_in[23];
    float* out = (float*)d_out;

    float* ws   = (float*)d_ws;
    float* FN   = ws;                   // (B*L,192) NHWC feature     1,572,864
    float* XN   = FN   + 1572864;       // PART-A / ln-out / CX / PART-C
    float* XP   = XN   + 1572864;       // (B,384,L) planar xp; PA after dw
    float* ZT   = XP   + 3145728;       // (B*L,384) z NHWC
    float* XCNH = ZT   + 3145728;       // (B*L,384) u NHWC; yg in-place
    float* DLT  = XCNH + 3145728;       // (B,L,4,384) delta->y; YN after merge
    float* HF   = DLT  + 12582912;      // carries (bk,c,n,d)         3,145,728
    float* WT14 = HF   + 3145728;       // transformed w c1..c4         129,024
    float* WT5  = WT14 + 129024;        // transformed w c5             110,592
    float* WX   = WT5  + 110592;        // padded x_proj_w (192,384)     73,728
    // total 28,612,096 floats = 109.1 MiB
    float* PA = XP;                     // 3,145,728 = NB*KD*NC*NST*DIM exactly
    float* CX = XN;                     // 1,572,864 = NB*LEN*192 exactly
    float* PART = XN;                   // conv partials (stage A & C)
    float* YN = DLT;                    // out_proj output NHWC (B*L,192)

    // weight transforms  (wt layout: (t, co, ci))
    k_wtr<<<dim3(72),  256, 0, stream>>>(c1w, WT14,          64, 32, 9 * 64 * 32);
    k_wtr<<<dim3(108), 256, 0, stream>>>(c2w, WT14 + 18432,  96, 32, 9 * 96 * 32);
    k_wtr<<<dim3(144), 256, 0, stream>>>(c3w, WT14 + 46080, 128, 32, 9 * 128 * 32);
    k_wtr<<<dim3(180), 256, 0, stream>>>(c4w, WT14 + 82944, 160, 32, 9 * 160 * 32);
    k_wtr<<<dim3(432), 256, 0, stream>>>(c5w, WT5,          192, 64, 9 * 192 * 64);
    k_wxp<<<dim3(288), 256, 0, stream>>>(xpw, WX);

    // stage A: dense conv block (implicit GEMM, halo-staged, b128 LDS)
    k_tr_in<<<dim3(HN, NB), 256, 0, stream>>>(x, FN);
    k_convg<0><<<dim3(64, 1, NB * 3), 256, 0, stream>>>(FN, DM, 64, 32, WT14, PART);
    k_ep_nhwc<<<dim3(1024), 256, 0, stream>>>(PART, c1b, FN, 64, 0.01f);
    k_convg<0><<<dim3(64, 1, NB * 3), 256, 0, stream>>>(FN, DM, 96, 32, WT14 + 18432, PART);
    k_ep_nhwc<<<dim3(1024), 256, 0, stream>>>(PART, c2b, FN, 96, 0.01f);
    k_convg<0><<<dim3(64, 1, NB * 3), 256, 0, stream>>>(FN, DM, 128, 32, WT14 + 46080, PART);
    k_ep_nhwc<<<dim3(1024), 256, 0, stream>>>(PART, c3b, FN, 128, 0.01f);
    k_convg<0><<<dim3(64, 1, NB * 3), 256, 0, stream>>>(FN, DM, 160, 32, WT14 + 82944, PART);
    k_ep_nhwc<<<dim3(1024), 256, 0, stream>>>(PART, c4b, FN, 160, 0.01f);

    // stage B: VSS block
    k_ln<<<dim3(NB * LEN / 4), 256, 0, stream>>>(FN, ln1g, ln1b, XN);
    k_gemm<<<dim3(LEN / 64, DIM / 64, NB), 256, 0, stream>>>(XN, DM, ipw, nullptr, XP, DIM, 0);
    k_gemm<<<dim3(LEN / 64, DIM / 64, NB), 256, 0, stream>>>(XN, DM, ipw + (size_t)DIM * DM, nullptr, ZT, DIM, 1);
    k_dw<<<dim3(HN, DIM / 64, NB), 256, 0, stream>>>(XP, dww, dwb, XCNH);
    k_gemm<<<dim3(LEN / 64, 3, NB), 256, 0, stream>>>(XCNH, DIM, WX, nullptr, CX, 192, 1);
    k_delta<<<dim3(LEN / 16, KD, NB), 384, 0, stream>>>(CX, dtw, dtb, DLT);
    k_scan_a<<<dim3(NC, KD, NB), 384, 0, stream>>>(XCNH, CX, alog, DLT, HF, PA);
    k_scan_b<<<dim3(NB * KD * NST * DIM / 256), 256, 0, stream>>>(HF, PA);
    k_scan_c<<<dim3(NC, KD, NB), 384, 0, stream>>>(XCNH, CX, alog, HF, DLT);
    k_merge<<<dim3(NB * LEN / 4), 256, 0, stream>>>(DLT, XCNH, dsv, ong, onb, ZT, XCNH);
    k_gemm<<<dim3(LEN / 64, DM / 64, NB), 256, 0, stream>>>(XCNH, DIM, opw, FN, YN, DM, 1);

    // stage C: final conv (implicit GEMM, planar out)
    k_convg<1><<<dim3(64, 2, NB * 3), 256, 0, stream>>>(YN, DM, 192, 64, WT5, PART);
    k_ep_pl<<<dim3(2048), 256, 0, stream>>>(PART, c5b, out);
}

// Round 12
// 450.139 us; speedup vs baseline: 1.1414x; 1.1414x over previous
//
#include <hip/hip_runtime.h>
#include <hip/hip_bf16.h>
#include <math.h>

// ---- problem constants ----
static constexpr int LEN = 4096;   // H*W
static constexpr int HN  = 64;     // H
static constexpr int WN  = 64;     // W
static constexpr int NB  = 2;      // batch
static constexpr int DM  = 192;    // d_model
static constexpr int DIM = 384;    // d_inner
static constexpr int NST = 16;     // n_state
static constexpr int DTR = 12;     // dt_rank
static constexpr int KD  = 4;      // directions
static constexpr int NC  = 64;     // scan chunks
static constexpr int CHL = LEN / NC; // 64 elements per chunk

// direction k seq-position -> pixel row index (uniform across a wave)
__device__ __forceinline__ int maprow(int k, int gl) {
    int g = (k & 2) ? (LEN - 1 - gl) : gl;
    return (k & 1) ? (((g & 63) << 6) | (g >> 6)) : g;
}

// ---------------------------------------------------------------------------
// weight transform: w (co,ci,3,3) -> wt (t, co, ci)   [ci contiguous]
__global__ void k_wtr(const float* __restrict__ w, float* __restrict__ wt,
                      int cin, int cout, int n)
{
    int idx = blockIdx.x * 256 + threadIdx.x;
    if (idx >= n) return;
    int ci = idx % cin; int r = idx / cin;
    int co = r % cout; int t = r / cout;
    wt[idx] = w[((size_t)(co * cin + ci)) * 9 + t];
}

// pad x_proj_w (4,44,384) -> WX (192,384), rows k*48+c (c<44), zero pad
__global__ void k_wxp(const float* __restrict__ xpw, float* __restrict__ WX)
{
    int idx = blockIdx.x * 256 + threadIdx.x;    // 192*384
    if (idx >= 192 * DIM) return;
    int row = idx / DIM, d = idx - row * DIM;
    int k = row / 48, c = row - k * 48;
    WX[idx] = (c < 44) ? xpw[((size_t)(k * 44 + c)) * DIM + d] : 0.f;
}

// ---------------------------------------------------------------------------
// x (B,64,L) planar -> FN NHWC cols [0,64)
__global__ void k_tr_in(const float* __restrict__ x, float* __restrict__ FN)
{
    __shared__ float t[64][65];
    int b = blockIdx.y, r = blockIdx.x;
    int tid = threadIdx.x;
#pragma unroll
    for (int i = 0; i < 16; ++i) {
        int idx = (i << 8) + tid;
        int c = idx >> 6, xc = idx & 63;
        t[c][xc] = x[((size_t)(b * 64 + c)) * LEN + r * WN + xc];
    }
    __syncthreads();
#pragma unroll
    for (int i = 0; i < 16; ++i) {
        int idx = (i << 8) + tid;
        int px = idx >> 6, c = idx & 63;
        FN[((size_t)(b * LEN + r * WN + px)) * DM + c] = t[c][px];
    }
}

// ---------------------------------------------------------------------------
// implicit-GEMM conv3x3, dy-split partials. tile 64px x 32oc.
// halo-staged As; Bs transposed [dx][oc][ci]; b128 LDS reads.
template<int PLANAR>
__global__ void __launch_bounds__(256) k_convg(
    const float* __restrict__ in, int cbuf, int cin, int cout,
    const float* __restrict__ wt,
    float* __restrict__ part)
{
    __shared__ float As[66][36];
    __shared__ float Bs[3][32][36];
    int zz = blockIdx.z;
    int b = zz / 3, s = zz % 3;
    int y0 = blockIdx.x;
    int n0 = blockIdx.y << 5;
    int tid = threadIdx.x;
    int tl = tid & 15, tn = (tid >> 4) << 1;
    int y = y0 + s - 1;
    bool yok = (unsigned)y < (unsigned)HN;
    const float* inb = in + ((size_t)b * LEN + (size_t)y * WN) * cbuf;
    float acc[4][2] = {};

    for (int ci0 = 0; ci0 < cin; ci0 += 32) {
#pragma unroll
        for (int it = 0; it < 3; ++it) {
            int fi = (it << 8) + tid;
            if (fi < 528) {                       // 66 rows x 8 quads
                int px = fi >> 3, ci4 = (fi & 7) << 2;
                int xx = px - 1;
                float4 v = make_float4(0.f, 0.f, 0.f, 0.f);
                if (yok && (unsigned)xx < (unsigned)WN)
                    v = *(const float4*)(inb + (size_t)xx * cbuf + ci0 + ci4);
                *(float4*)(&As[px][ci4]) = v;
            }
        }
#pragma unroll
        for (int dx = 0; dx < 3; ++dx) {
            int oc = tid >> 3, ci4 = (tid & 7) << 2;
            int t = s * 3 + dx;
            float4 wv = *(const float4*)(wt + ((size_t)(t * cout + n0 + oc)) * cin + ci0 + ci4);
            *(float4*)(&Bs[dx][oc][ci4]) = wv;
        }
        __syncthreads();
#pragma unroll
        for (int dx = 0; dx < 3; ++dx) {
#pragma unroll
            for (int k = 0; k < 32; k += 4) {
                float4 b0 = *(const float4*)(&Bs[dx][tn][k]);
                float4 b1 = *(const float4*)(&Bs[dx][tn + 1][k]);
#pragma unroll
                for (int i = 0; i < 4; ++i) {
                    float4 a = *(const float4*)(&As[tl + (i << 4) + dx][k]);
                    acc[i][0] += a.x * b0.x + a.y * b0.y + a.z * b0.z + a.w * b0.w;
                    acc[i][1] += a.x * b1.x + a.y * b1.y + a.z * b1.z + a.w * b1.w;
                }
            }
        }
        __syncthreads();
    }
    if (PLANAR) {
#pragma unroll
        for (int j = 0; j < 2; ++j) {
            float* pp = part + ((size_t)((s * NB + b) * 64 + n0 + tn + j)) * LEN + y0 * WN + tl;
#pragma unroll
            for (int i = 0; i < 4; ++i) pp[i << 4] = acc[i][j];
        }
    } else {
#pragma unroll
        for (int i = 0; i < 4; ++i) {
            float* pp = part + (((size_t)(s * NB + b) * LEN) + y0 * WN + tl + (i << 4)) * 32 + tn;
            pp[0] = acc[i][0]; pp[1] = acc[i][1];
        }
    }
}

// epilogue: sum 3 dy-partials + bias + leakyrelu -> FN NHWC col block
__global__ void k_ep_nhwc(const float* __restrict__ part, const float* __restrict__ bias,
                          float* __restrict__ FN, int co0, float slope)
{
    int idx = blockIdx.x * 256 + threadIdx.x;
    int co = idx & 31, px = idx >> 5;
    const size_t S = (size_t)NB * LEN * 32;
    float v = part[idx] + part[S + idx] + part[2 * S + idx] + bias[co];
    v = v > 0.f ? v : v * slope;
    FN[(size_t)px * DM + co0 + co] = v;
}

// epilogue: sum 3 dy-partials + bias -> planar out (B,64,L)
__global__ void k_ep_pl(const float* __restrict__ part, const float* __restrict__ bias,
                        float* __restrict__ out)
{
    int idx = blockIdx.x * 256 + threadIdx.x;
    int oc = (idx >> 12) & 63;
    const size_t S = (size_t)NB * 64 * LEN;
    float v = part[idx] + part[S + idx] + part[2 * S + idx] + bias[oc];
    out[idx] = v;
}

// ---------------------------------------------------------------------------
// LayerNorm over 192 channels, NHWC in/out
__global__ void k_ln(const float* __restrict__ FN, const float* __restrict__ g,
                     const float* __restrict__ be, float* __restrict__ xn)
{
    int lane = threadIdx.x & 63;
    int pix  = (blockIdx.x << 2) + (threadIdx.x >> 6);
    const float* fp = FN + (size_t)pix * DM;
    float v0 = fp[lane];
    float v1 = fp[lane + 64];
    float v2 = fp[lane + 128];
    float s = v0 + v1 + v2, ss = v0 * v0 + v1 * v1 + v2 * v2;
#pragma unroll
    for (int off = 1; off < 64; off <<= 1) { s += __shfl_xor(s, off); ss += __shfl_xor(ss, off); }
    float mu = s * (1.f / 192.f);
    float var = ss * (1.f / 192.f) - mu * mu;
    float rstd = rsqrtf(var + 1e-5f);
    float* op = xn + (size_t)pix * DM;
    op[lane]       = (v0 - mu) * rstd * g[lane]       + be[lane];
    op[lane + 64]  = (v1 - mu) * rstd * g[lane + 64]  + be[lane + 64];
    op[lane + 128] = (v2 - mu) * rstd * g[lane + 128] + be[lane + 128];
}

// ---------------------------------------------------------------------------
// tiled f32 GEMM (round-10 proven form): A (B*L,K) NHWC x Wt (N,K)
// -> planar (B,outC,L) or NHWC.
__global__ void __launch_bounds__(256) k_gemm(
    const float* __restrict__ A, int K,
    const float* __restrict__ Wt,
    const float* __restrict__ res,
    float* __restrict__ Cp, int outC, int nhwc)
{
    __shared__ float As[64][65];
    __shared__ float Bs[64][65];
    int b  = blockIdx.z;
    int l0 = blockIdx.x << 6, n0 = blockIdx.y << 6;
    int tid = threadIdx.x;
    int tl = (tid & 15) << 2, tn = (tid >> 4) << 2;
    float acc[4][4] = {};

    for (int k0 = 0; k0 < K; k0 += 64) {
#pragma unroll
        for (int s = 0; s < 4; ++s) {
            int e = (s << 10) + (tid << 2);
            int row = e >> 6, col = e & 63;
            float4 av = *(const float4*)(A + ((size_t)b * LEN + l0 + row) * K + k0 + col);
            As[row][col] = av.x; As[row][col + 1] = av.y; As[row][col + 2] = av.z; As[row][col + 3] = av.w;
            float4 wv = *(const float4*)(Wt + (size_t)(n0 + row) * K + k0 + col);
            Bs[row][col] = wv.x; Bs[row][col + 1] = wv.y; Bs[row][col + 2] = wv.z; Bs[row][col + 3] = wv.w;
        }
        __syncthreads();
#pragma unroll
        for (int kk = 0; kk < 64; ++kk) {
            float a0 = As[tl][kk], a1 = As[tl + 1][kk], a2 = As[tl + 2][kk], a3 = As[tl + 3][kk];
            float b0 = Bs[tn][kk], b1 = Bs[tn + 1][kk], b2 = Bs[tn + 2][kk], b3 = Bs[tn + 3][kk];
            acc[0][0] += a0 * b0; acc[0][1] += a0 * b1; acc[0][2] += a0 * b2; acc[0][3] += a0 * b3;
            acc[1][0] += a1 * b0; acc[1][1] += a1 * b1; acc[1][2] += a1 * b2; acc[1][3] += a1 * b3;
            acc[2][0] += a2 * b0; acc[2][1] += a2 * b1; acc[2][2] += a2 * b2; acc[2][3] += a2 * b3;
            acc[3][0] += a3 * b0; acc[3][1] += a3 * b1; acc[3][2] += a3 * b2; acc[3][3] += a3 * b3;
        }
        __syncthreads();
    }
    if (!nhwc) {
#pragma unroll
        for (int j = 0; j < 4; ++j) {
            size_t o = ((size_t)(b * outC) + n0 + tn + j) * LEN + l0 + tl;
            float4 v;
            v.x = acc[0][j]; v.y = acc[1][j]; v.z = acc[2][j]; v.w = acc[3][j];
            if (res) {
                float4 r = *(const float4*)(res + o);
                v.x += r.x; v.y += r.y; v.z += r.z; v.w += r.w;
            }
            *(float4*)(Cp + o) = v;
        }
    } else {
#pragma unroll
        for (int i = 0; i < 4; ++i) {
            size_t o = ((size_t)b * LEN + l0 + tl + i) * outC + n0 + tn;
            float4 v;
            v.x = acc[i][0]; v.y = acc[i][1]; v.z = acc[i][2]; v.w = acc[i][3];
            if (res) {
                float4 r = *(const float4*)(res + o);
                v.x += r.x; v.y += r.y; v.z += r.z; v.w += r.w;
            }
            *(float4*)(Cp + o) = v;
        }
    }
}

// ---------------------------------------------------------------------------
// fused in_proj GEMM: K=192 fixed. blockIdx.y in [0,12):
// y<6 -> xp half, planar into XP (B,384,L); y>=6 -> z half, NHWC into ZT.
__global__ void __launch_bounds__(256) k_gemm_ip(
    const float* __restrict__ A, const float* __restrict__ Wt,
    float* __restrict__ XP, float* __restrict__ ZT)
{
    __shared__ float As[64][65];
    __shared__ float Bs[64][65];
    int b  = blockIdx.z;
    int l0 = blockIdx.x << 6, n0 = blockIdx.y << 6;
    int tid = threadIdx.x;
    int tl = (tid & 15) << 2, tn = (tid >> 4) << 2;
    float acc[4][4] = {};

    for (int k0 = 0; k0 < DM; k0 += 64) {
#pragma unroll
        for (int s = 0; s < 4; ++s) {
            int e = (s << 10) + (tid << 2);
            int row = e >> 6, col = e & 63;
            float4 av = *(const float4*)(A + ((size_t)b * LEN + l0 + row) * DM + k0 + col);
            As[row][col] = av.x; As[row][col + 1] = av.y; As[row][col + 2] = av.z; As[row][col + 3] = av.w;
            float4 wv = *(const float4*)(Wt + (size_t)(n0 + row) * DM + k0 + col);
            Bs[row][col] = wv.x; Bs[row][col + 1] = wv.y; Bs[row][col + 2] = wv.z; Bs[row][col + 3] = wv.w;
        }
        __syncthreads();
#pragma unroll
        for (int kk = 0; kk < 64; ++kk) {
            float a0 = As[tl][kk], a1 = As[tl + 1][kk], a2 = As[tl + 2][kk], a3 = As[tl + 3][kk];
            float b0 = Bs[tn][kk], b1 = Bs[tn + 1][kk], b2 = Bs[tn + 2][kk], b3 = Bs[tn + 3][kk];
            acc[0][0] += a0 * b0; acc[0][1] += a0 * b1; acc[0][2] += a0 * b2; acc[0][3] += a0 * b3;
            acc[1][0] += a1 * b0; acc[1][1] += a1 * b1; acc[1][2] += a1 * b2; acc[1][3] += a1 * b3;
            acc[2][0] += a2 * b0; acc[2][1] += a2 * b1; acc[2][2] += a2 * b2; acc[2][3] += a2 * b3;
            acc[3][0] += a3 * b0; acc[3][1] += a3 * b1; acc[3][2] += a3 * b2; acc[3][3] += a3 * b3;
        }
        __syncthreads();
    }
    if (blockIdx.y < 6) {
        // planar xp half
#pragma unroll
        for (int j = 0; j < 4; ++j) {
            size_t o = ((size_t)(b * DIM) + n0 + tn + j) * LEN + l0 + tl;
            float4 v;
            v.x = acc[0][j]; v.y = acc[1][j]; v.z = acc[2][j]; v.w = acc[3][j];
            *(float4*)(XP + o) = v;
        }
    } else {
        // NHWC z half
        int nz = n0 - DIM;
#pragma unroll
        for (int i = 0; i < 4; ++i) {
            size_t o = ((size_t)b * LEN + l0 + tl + i) * DIM + nz + tn;
            float4 v;
            v.x = acc[i][0]; v.y = acc[i][1]; v.z = acc[i][2]; v.w = acc[i][3];
            *(float4*)(ZT + o) = v;
        }
    }
}

// ---------------------------------------------------------------------------
// depthwise conv3x3 + SiLU : xp planar (B,384,L) -> unh NHWC (B*L, 384)
__global__ void __launch_bounds__(256) k_dw(
    const float* __restrict__ xp, const float* __restrict__ w,
    const float* __restrict__ bias, float* __restrict__ unh)
{
    __shared__ float t[64][65];
    int b = blockIdx.z, cg = blockIdx.y, r = blockIdx.x;
    int x = threadIdx.x & 63, cs = threadIdx.x >> 6;
#pragma unroll
    for (int i = 0; i < 16; ++i) {
        int c = cg * 64 + cs * 16 + i;
        const float* ip = xp + ((size_t)(b * DIM + c)) * LEN;
        const float* wp = w + c * 9;
        float acc = bias[c];
#pragma unroll
        for (int dy = 0; dy < 3; ++dy) {
            int ry = r + dy - 1;
            if ((unsigned)ry >= (unsigned)HN) continue;
#pragma unroll
            for (int dx = 0; dx < 3; ++dx) {
                int xx = x + dx - 1;
                if ((unsigned)xx >= (unsigned)WN) continue;
                acc += ip[ry * WN + xx] * wp[dy * 3 + dx];
            }
        }
        acc = acc / (1.f + __expf(-acc));
        t[x][cs * 16 + i] = acc;
    }
    __syncthreads();
    float* op = unh + ((size_t)b * LEN + r * 64) * DIM + cg * 64;
#pragma unroll
    for (int i = 0; i < 16; ++i) {
        int idx = (i << 8) + threadIdx.x;
        int px = idx >> 6, cc = idx & 63;
        op[(size_t)px * DIM + cc] = t[px][cc];
    }
}

// ---------------------------------------------------------------------------
// delta = softplus(dtb + CX[:, k*48+0..12] @ dtw[k]^T), pixel-order output
__global__ void __launch_bounds__(384) k_delta(
    const float* __restrict__ CX, const float* __restrict__ dtw,
    const float* __restrict__ dtb, float* __restrict__ dlt)
{
    __shared__ float cs[16][12];
    int b = blockIdx.z, k = blockIdx.y;
    int lp0 = blockIdx.x << 4;
    int tid = threadIdx.x;
    if (tid < 192) {
        int p = tid / 12, r = tid - p * 12;
        cs[p][r] = CX[((size_t)(b * LEN) + lp0 + p) * 192 + k * 48 + r];
    }
    __syncthreads();
    float wt[DTR];
    const float* wp = dtw + ((size_t)(k * DIM) + tid) * DTR;
#pragma unroll
    for (int r = 0; r < DTR; ++r) wt[r] = wp[r];
    float bv = dtb[k * DIM + tid];
    float* dbase = dlt + (((size_t)(b * LEN) + lp0) * KD + k) * DIM + tid;
#pragma unroll
    for (int p = 0; p < 16; ++p) {
        float s = bv;
#pragma unroll
        for (int r = 0; r < DTR; ++r) s += cs[p][r] * wt[r];
        s = (s > 20.f) ? s : __logf(1.f + __expf(s));
        dbase[(size_t)p * KD * DIM] = s;
    }
}

// ---------------------------------------------------------------------------
// chunked scan phase A. thread = d; 16 states in registers; B staged from CX.
// geometric-A fast path (runtime verified, exp fallback kept).
__global__ void __launch_bounds__(384) k_scan_a(
    const float* __restrict__ unh, const float* __restrict__ CX,
    const float* __restrict__ alog, const float* __restrict__ dlt,
    float* __restrict__ hf, float* __restrict__ pA)
{
    __shared__ float bs[CHL * 16];
    int b = blockIdx.z, k = blockIdx.y, c = blockIdx.x;
    int d = threadIdx.x;
    for (int i = threadIdx.x; i < CHL * 16; i += 384) {
        int l = i >> 4, n = i & 15;
        int row = maprow(k, c * CHL + l);
        bs[i] = CX[((size_t)(b * LEN) + row) * 192 + k * 48 + 12 + n];
    }
    __syncthreads();

    float A[16], h[16];
    const float* ap = alog + ((size_t)(k * DIM + d)) * NST;
#pragma unroll
    for (int q = 0; q < 4; ++q) {
        float4 av = *(const float4*)(ap + q * 4);
        A[q * 4]     = -__expf(av.x); A[q * 4 + 1] = -__expf(av.y);
        A[q * 4 + 2] = -__expf(av.z); A[q * 4 + 3] = -__expf(av.w);
    }
    bool geo = true;
#pragma unroll
    for (int n = 1; n < 16; ++n)
        geo = geo && (fabsf(A[n] - (n + 1) * A[0]) <= 1e-4f * (n + 1) * fabsf(A[0]));
#pragma unroll
    for (int n = 0; n < 16; ++n) h[n] = 0.f;

    const float* ub = unh + (size_t)b * LEN * DIM + d;
    const float* db = dlt + ((size_t)(b * LEN) * KD + k) * DIM + d;
    size_t base = (((size_t)((b * KD + k) * NC + c)) * NST) * DIM + d;

    float dv0[4], uu0[4], dv1[4], uu1[4];
#pragma unroll
    for (int j = 0; j < 4; ++j) {
        int row = maprow(k, c * CHL + j);
        dv0[j] = db[(size_t)row * KD * DIM];
        uu0[j] = ub[(size_t)row * DIM];
    }
    if (geo) {
        float A0 = A[0];
        float p0 = 1.f;
        for (int l0 = 0; l0 < CHL; l0 += 4) {
            if (l0 + 4 < CHL) {
#pragma unroll
                for (int j = 0; j < 4; ++j) {
                    int row = maprow(k, c * CHL + l0 + 4 + j);
                    dv1[j] = db[(size_t)row * KD * DIM];
                    uu1[j] = ub[(size_t)row * DIM];
                }
            }
#pragma unroll
            for (int j = 0; j < 4; ++j) {
                float du = dv0[j] * uu0[j];
                const float* bl = bs + (l0 + j) * 16;
                float qv = __expf(dv0[j] * A0);
                float pw = qv;
                h[0] = qv * h[0] + du * bl[0];
#pragma unroll
                for (int n = 1; n < 16; ++n) { pw *= qv; h[n] = pw * h[n] + du * bl[n]; }
                p0 *= qv;
            }
#pragma unroll
            for (int j = 0; j < 4; ++j) { dv0[j] = dv1[j]; uu0[j] = uu1[j]; }
        }
        float pw = 1.f;
#pragma unroll
        for (int n = 0; n < 16; ++n) {
            pw *= p0;
            hf[base + (size_t)n * DIM] = h[n];
            pA[base + (size_t)n * DIM] = pw;
        }
    } else {
        float p[16];
#pragma unroll
        for (int n = 0; n < 16; ++n) p[n] = 1.f;
        for (int l0 = 0; l0 < CHL; l0 += 4) {
            if (l0 + 4 < CHL) {
#pragma unroll
                for (int j = 0; j < 4; ++j) {
                    int row = maprow(k, c * CHL + l0 + 4 + j);
                    dv1[j] = db[(size_t)row * KD * DIM];
                    uu1[j] = ub[(size_t)row * DIM];
                }
            }
#pragma unroll
            for (int j = 0; j < 4; ++j) {
                float du = dv0[j] * uu0[j];
                const float* bl = bs + (l0 + j) * 16;
#pragma unroll
                for (int n = 0; n < 16; ++n) {
                    float dA = __expf(dv0[j] * A[n]);
                    h[n] = dA * h[n] + du * bl[n];
                    p[n] *= dA;
                }
            }
#pragma unroll
            for (int j = 0; j < 4; ++j) { dv0[j] = dv1[j]; uu0[j] = uu1[j]; }
        }
#pragma unroll
        for (int n = 0; n < 16; ++n) {
            hf[base + (size_t)n * DIM] = h[n];
            pA[base + (size_t)n * DIM] = p[n];
        }
    }
}

// phase B: serial carry combine over chunks; hf[c] overwritten with carry-IN.
__global__ void k_scan_b(float* __restrict__ hf, const float* __restrict__ pA)
{
    int s = blockIdx.x * 256 + threadIdx.x;          // NB*KD*NST*DIM = 49152
    int bk = s / (NST * DIM);
    int r  = s - bk * (NST * DIM);
    size_t base = (size_t)bk * NC * NST * DIM + r;
    const size_t cs = (size_t)NST * DIM;
    float car = 0.f;
#pragma unroll 8
    for (int c = 0; c < NC; ++c) {
        float hfc = hf[base + c * cs], pc = pA[base + c * cs];
        hf[base + c * cs] = car;
        car = pc * car + hfc;
    }
}

// phase C: re-run chunk from carry-in; geometric-A fast path; y pixel-order.
__global__ void __launch_bounds__(384) k_scan_c(
    const float* __restrict__ unh, const float* __restrict__ CX,
    const float* __restrict__ alog, const float* __restrict__ hf,
    float* __restrict__ dlt)
{
    __shared__ float bs[CHL * 32];
    int b = blockIdx.z, k = blockIdx.y, c = blockIdx.x;
    int d = threadIdx.x;
    for (int i = threadIdx.x; i < CHL * 32; i += 384) {
        int l = i >> 5, n = i & 31;
        int row = maprow(k, c * CHL + l);
        bs[i] = CX[((size_t)(b * LEN) + row) * 192 + k * 48 + 12 + n];
    }
    __syncthreads();

    float A[16], h[16];
    const float* ap = alog + ((size_t)(k * DIM + d)) * NST;
#pragma unroll
    for (int q = 0; q < 4; ++q) {
        float4 av = *(const float4*)(ap + q * 4);
        A[q * 4]     = -__expf(av.x); A[q * 4 + 1] = -__expf(av.y);
        A[q * 4 + 2] = -__expf(av.z); A[q * 4 + 3] = -__expf(av.w);
    }
    bool geo = true;
#pragma unroll
    for (int n = 1; n < 16; ++n)
        geo = geo && (fabsf(A[n] - (n + 1) * A[0]) <= 1e-4f * (n + 1) * fabsf(A[0]));
    size_t base = (((size_t)((b * KD + k) * NC + c)) * NST) * DIM + d;
#pragma unroll
    for (int n = 0; n < 16; ++n) h[n] = hf[base + (size_t)n * DIM];

    const float* ub = unh + (size_t)b * LEN * DIM + d;
    float* db = dlt + ((size_t)(b * LEN) * KD + k) * DIM + d;

    int rows0[4], rows1[4];
    float dv0[4], uu0[4], dv1[4], uu1[4];
#pragma unroll
    for (int j = 0; j < 4; ++j) {
        rows0[j] = maprow(k, c * CHL + j);
        dv0[j] = db[(size_t)rows0[j] * KD * DIM];
        uu0[j] = ub[(size_t)rows0[j] * DIM];
    }
    if (geo) {
        float A0 = A[0];
        for (int l0 = 0; l0 < CHL; l0 += 4) {
            if (l0 + 4 < CHL) {
#pragma unroll
                for (int j = 0; j < 4; ++j) {
                    rows1[j] = maprow(k, c * CHL + l0 + 4 + j);
                    dv1[j] = db[(size_t)rows1[j] * KD * DIM];
                    uu1[j] = ub[(size_t)rows1[j] * DIM];
                }
            }
            float ys[4];
#pragma unroll
            for (int j = 0; j < 4; ++j) {
                const float* bl = bs + (l0 + j) * 32;
                float du = dv0[j] * uu0[j];
                float qv = __expf(dv0[j] * A0);
                float pw = qv;
                h[0] = qv * h[0] + du * bl[0];
                float y = h[0] * bl[16];
#pragma unroll
                for (int n = 1; n < 16; ++n) {
                    pw *= qv;
                    h[n] = pw * h[n] + du * bl[n];
                    y += h[n] * bl[16 + n];
                }
                ys[j] = y;
            }
#pragma unroll
            for (int j = 0; j < 4; ++j) db[(size_t)rows0[j] * KD * DIM] = ys[j];
#pragma unroll
            for (int j = 0; j < 4; ++j) { rows0[j] = rows1[j]; dv0[j] = dv1[j]; uu0[j] = uu1[j]; }
        }
    } else {
        for (int l0 = 0; l0 < CHL; l0 += 4) {
            if (l0 + 4 < CHL) {
#pragma unroll
                for (int j = 0; j < 4; ++j) {
                    rows1[j] = maprow(k, c * CHL + l0 + 4 + j);
                    dv1[j] = db[(size_t)rows1[j] * KD * DIM];
                    uu1[j] = ub[(size_t)rows1[j] * DIM];
                }
            }
            float ys[4];
#pragma unroll
            for (int j = 0; j < 4; ++j) {
                const float* bl = bs + (l0 + j) * 32;
                float du = dv0[j] * uu0[j];
                float y = 0.f;
#pragma unroll
                for (int n = 0; n < 16; ++n) {
                    float dA = __expf(dv0[j] * A[n]);
                    h[n] = dA * h[n] + du * bl[n];
                    y += h[n] * bl[16 + n];
                }
                ys[j] = y;
            }
#pragma unroll
            for (int j = 0; j < 4; ++j) db[(size_t)rows0[j] * KD * DIM] = ys[j];
#pragma unroll
            for (int j = 0; j < 4; ++j) { rows0[j] = rows1[j]; dv0[j] = dv1[j]; uu0[j] = uu1[j]; }
        }
    }
}

// ---------------------------------------------------------------------------
// merge 4 directions + D*u + out-LN + silu(z) gate -> yg NHWC (in-place over unh)
__global__ void k_merge(const float* __restrict__ y4, const float* __restrict__ unh,
                        const float* __restrict__ Ds, const float* __restrict__ ong,
                        const float* __restrict__ onb, const float* __restrict__ zt,
                        float* __restrict__ yg)
{
    int lane = threadIdx.x & 63;
    int pix = (blockIdx.x << 2) + (threadIdx.x >> 6);
    const float* yp = y4 + (size_t)pix * KD * DIM;
    const float* up = unh + (size_t)pix * DIM;
    float v[6]; float s = 0.f, ss = 0.f;
#pragma unroll
    for (int j = 0; j < 6; ++j) {
        int d = lane + (j << 6);
        float y = yp[d] + yp[DIM + d] + yp[2 * DIM + d] + yp[3 * DIM + d];
        float dsum = Ds[d] + Ds[DIM + d] + Ds[2 * DIM + d] + Ds[3 * DIM + d];
        y += dsum * up[d];
        v[j] = y; s += y; ss += y * y;
    }
#pragma unroll
    for (int off = 1; off < 64; off <<= 1) { s += __shfl_xor(s, off); ss += __shfl_xor(ss, off); }
    float mu = s * (1.f / 384.f);
    float var = ss * (1.f / 384.f) - mu * mu;
    float rstd = rsqrtf(var + 1e-5f);
    const float* zp = zt + (size_t)pix * DIM;
    float* op = yg + (size_t)pix * DIM;
#pragma unroll
    for (int j = 0; j < 6; ++j) {
        int d = lane + (j << 6);
        float zz = zp[d];
        float gate = zz / (1.f + __expf(-zz));
        op[d] = ((v[j] - mu) * rstd * ong[d] + onb[d]) * gate;
    }
}

// ---------------------------------------------------------------------------
extern "C" void kernel_launch(void* const* d_in, const int* in_sizes, int n_in,
                              void* d_out, int out_size, void* d_ws, size_t ws_size,
                              hipStream_t stream)
{
    const float* x    = (const float*)d_in[0];
    const float* c1w  = (const float*)d_in[1];  const float* c1b = (const float*)d_in[2];
    const float* c2w  = (const float*)d_in[3];  const float* c2b = (const float*)d_in[4];
    const float* c3w  = (const float*)d_in[5];  const float* c3b = (const float*)d_in[6];
    const float* c4w  = (const float*)d_in[7];  const float* c4b = (const float*)d_in[8];
    const float* c5w  = (const float*)d_in[9];  const float* c5b = (const float*)d_in[10];
    const float* ln1g = (const float*)d_in[11]; const float* ln1b= (const float*)d_in[12];
    const float* ipw  = (const float*)d_in[13];
    const float* dww  = (const float*)d_in[14]; const float* dwb = (const float*)d_in[15];
    const float* xpw  = (const float*)d_in[16];
    const float* dtw  = (const float*)d_in[17]; const float* dtb = (const float*)d_in[18];
    const float* alog = (const float*)d_in[19]; const float* dsv = (const float*)d_in[20];
    const float* ong  = (const float*)d_in[21]; const float* onb = (const float*)d_in[22];
    const float* opw  = (const float*)d_in[23];
    float* out = (float*)d_out;

    float* ws   = (float*)d_ws;
    float* FN   = ws;                   // (B*L,192) NHWC feature     1,572,864
    float* XN   = FN   + 1572864;       // PART-A / ln-out / CX / PART-C
    float* XP   = XN   + 1572864;       // (B,384,L) planar xp; PA after dw
    float* ZT   = XP   + 3145728;       // (B*L,384) z NHWC
    float* XCNH = ZT   + 3145728;       // (B*L,384) u NHWC; yg in-place
    float* DLT  = XCNH + 3145728;       // (B,L,4,384) delta->y; YN after merge
    float* HF   = DLT  + 12582912;      // carries (bk,c,n,d)         3,145,728
    float* WT14 = HF   + 3145728;       // transformed w c1..c4         129,024
    float* WT5  = WT14 + 129024;        // transformed w c5             110,592
    float* WX   = WT5  + 110592;        // padded x_proj_w (192,384)     73,728
    // total 28,612,096 floats = 109.1 MiB
    float* PA = XP;                     // 3,145,728 = NB*KD*NC*NST*DIM exactly
    float* CX = XN;                     // 1,572,864 = NB*LEN*192 exactly
    float* PART = XN;                   // conv partials (stage A & C)
    float* YN = DLT;                    // out_proj output NHWC (B*L,192)

    // weight transforms  (wt layout: (t, co, ci))
    k_wtr<<<dim3(72),  256, 0, stream>>>(c1w, WT14,          64, 32, 9 * 64 * 32);
    k_wtr<<<dim3(108), 256, 0, stream>>>(c2w, WT14 + 18432,  96, 32, 9 * 96 * 32);
    k_wtr<<<dim3(144), 256, 0, stream>>>(c3w, WT14 + 46080, 128, 32, 9 * 128 * 32);
    k_wtr<<<dim3(180), 256, 0, stream>>>(c4w, WT14 + 82944, 160, 32, 9 * 160 * 32);
    k_wtr<<<dim3(432), 256, 0, stream>>>(c5w, WT5,          192, 64, 9 * 192 * 64);
    k_wxp<<<dim3(288), 256, 0, stream>>>(xpw, WX);

    // stage A: dense conv block (implicit GEMM, halo-staged, b128 LDS)
    k_tr_in<<<dim3(HN, NB), 256, 0, stream>>>(x, FN);
    k_convg<0><<<dim3(64, 1, NB * 3), 256, 0, stream>>>(FN, DM, 64, 32, WT14, PART);
    k_ep_nhwc<<<dim3(1024), 256, 0, stream>>>(PART, c1b, FN, 64, 0.01f);
    k_convg<0><<<dim3(64, 1, NB * 3), 256, 0, stream>>>(FN, DM, 96, 32, WT14 + 18432, PART);
    k_ep_nhwc<<<dim3(1024), 256, 0, stream>>>(PART, c2b, FN, 96, 0.01f);
    k_convg<0><<<dim3(64, 1, NB * 3), 256, 0, stream>>>(FN, DM, 128, 32, WT14 + 46080, PART);
    k_ep_nhwc<<<dim3(1024), 256, 0, stream>>>(PART, c3b, FN, 128, 0.01f);
    k_convg<0><<<dim3(64, 1, NB * 3), 256, 0, stream>>>(FN, DM, 160, 32, WT14 + 82944, PART);
    k_ep_nhwc<<<dim3(1024), 256, 0, stream>>>(PART, c4b, FN, 160, 0.01f);

    // stage B: VSS block
    k_ln<<<dim3(NB * LEN / 4), 256, 0, stream>>>(FN, ln1g, ln1b, XN);
    k_gemm_ip<<<dim3(LEN / 64, 12, NB), 256, 0, stream>>>(XN, ipw, XP, ZT);
    k_dw<<<dim3(HN, DIM / 64, NB), 256, 0, stream>>>(XP, dww, dwb, XCNH);
    k_gemm<<<dim3(LEN / 64, 3, NB), 256, 0, stream>>>(XCNH, DIM, WX, nullptr, CX, 192, 1);
    k_delta<<<dim3(LEN / 16, KD, NB), 384, 0, stream>>>(CX, dtw, dtb, DLT);
    k_scan_a<<<dim3(NC, KD, NB), 384, 0, stream>>>(XCNH, CX, alog, DLT, HF, PA);
    k_scan_b<<<dim3(NB * KD * NST * DIM / 256), 256, 0, stream>>>(HF, PA);
    k_scan_c<<<dim3(NC, KD, NB), 384, 0, stream>>>(XCNH, CX, alog, HF, DLT);
    k_merge<<<dim3(NB * LEN / 4), 256, 0, stream>>>(DLT, XCNH, dsv, ong, onb, ZT, XCNH);
    k_gemm<<<dim3(LEN / 64, DM / 64, NB), 256, 0, stream>>>(XCNH, DIM, opw, FN, YN, DM, 1);

    // stage C: final conv (implicit GEMM, planar out)
    k_convg<1><<<dim3(64, 2, NB * 3), 256, 0, stream>>>(YN, DM, 192, 64, WT5, PART);
    k_ep_pl<<<dim3(2048), 256, 0, stream>>>(PART, c5b, out);
}

// Round 13
// 363.937 us; speedup vs baseline: 1.4118x; 1.2369x over previous
//
#include <hip/hip_runtime.h>
#include <hip/hip_bf16.h>
#include <math.h>

// ---- problem constants ----
static constexpr int LEN = 4096;   // H*W
static constexpr int HN  = 64;     // H
static constexpr int WN  = 64;     // W
static constexpr int NB  = 2;      // batch
static constexpr int DM  = 192;    // d_model
static constexpr int DIM = 384;    // d_inner
static constexpr int NST = 16;     // n_state
static constexpr int DTR = 12;     // dt_rank
static constexpr int KD  = 4;      // directions
static constexpr int NC  = 64;     // scan chunks
static constexpr int CHL = LEN / NC; // 64 elements per chunk

typedef __attribute__((ext_vector_type(8))) short bfrag;
typedef __attribute__((ext_vector_type(4))) float facc;

__device__ __forceinline__ unsigned short f2bf(float x) {
    unsigned int u = __float_as_uint(x);
    return (unsigned short)((u + 0x7FFFu + ((u >> 16) & 1u)) >> 16);
}

// direction k seq-position -> pixel row index (uniform across a wave)
__device__ __forceinline__ int maprow(int k, int gl) {
    int g = (k & 2) ? (LEN - 1 - gl) : gl;
    return (k & 1) ? (((g & 63) << 6) | (g >> 6)) : g;
}

// ---------------------------------------------------------------------------
// weight transform: w (co,ci,3,3) -> wt (t, ci, co)   [r10-proven layout]
__global__ void k_wtr(const float* __restrict__ w, float* __restrict__ wt,
                      int cin, int cout, int n)
{
    int idx = blockIdx.x * 256 + threadIdx.x;
    if (idx >= n) return;
    int co = idx % cout; int r = idx / cout;
    int ci = r % cin; int t = r / cin;
    wt[idx] = w[((size_t)(co * cin + ci)) * 9 + t];
}

// pad x_proj_w (4,44,384) -> WX (192,384), rows k*48+c (c<44), zero pad
__global__ void k_wxp(const float* __restrict__ xpw, float* __restrict__ WX)
{
    int idx = blockIdx.x * 256 + threadIdx.x;    // 192*384
    if (idx >= 192 * DIM) return;
    int row = idx / DIM, d = idx - row * DIM;
    int k = row / 48, c = row - k * 48;
    WX[idx] = (c < 44) ? xpw[((size_t)(k * 44 + c)) * DIM + d] : 0.f;
}

// ---------------------------------------------------------------------------
// x (B,64,L) planar -> FN NHWC cols [0,64)
__global__ void k_tr_in(const float* __restrict__ x, float* __restrict__ FN)
{
    __shared__ float t[64][65];
    int b = blockIdx.y, r = blockIdx.x;
    int tid = threadIdx.x;
#pragma unroll
    for (int i = 0; i < 16; ++i) {
        int idx = (i << 8) + tid;
        int c = idx >> 6, xc = idx & 63;
        t[c][xc] = x[((size_t)(b * 64 + c)) * LEN + r * WN + xc];
    }
    __syncthreads();
#pragma unroll
    for (int i = 0; i < 16; ++i) {
        int idx = (i << 8) + tid;
        int px = idx >> 6, c = idx & 63;
        FN[((size_t)(b * LEN + r * WN + px)) * DM + c] = t[c][px];
    }
}

// ---------------------------------------------------------------------------
// implicit-GEMM conv3x3 (r10-proven): halo-staged As, scalar LDS reads.
template<int PLANAR>
__global__ void __launch_bounds__(256) k_convg(
    const float* __restrict__ in, int cbuf, int cin,
    const float* __restrict__ wt, int wstride,
    float* __restrict__ part)
{
    __shared__ float As[66][36];
    __shared__ float Bs[3][32][33];
    int zz = blockIdx.z;
    int b = zz / 3, s = zz % 3;
    int y0 = blockIdx.x;
    int n0 = blockIdx.y << 5;
    int tid = threadIdx.x;
    int tl = tid & 15, tn = (tid >> 4) << 1;
    int y = y0 + s - 1;
    bool yok = (unsigned)y < (unsigned)HN;
    const float* inb = in + ((size_t)b * LEN + (size_t)y * WN) * cbuf;
    float acc[4][2] = {};

    for (int ci0 = 0; ci0 < cin; ci0 += 32) {
#pragma unroll
        for (int it = 0; it < 3; ++it) {
            int fi = (it << 8) + tid;
            if (fi < 528) {
                int px = fi >> 3, ci4 = (fi & 7) << 2;
                int xx = px - 1;
                float4 v = make_float4(0.f, 0.f, 0.f, 0.f);
                if (yok && (unsigned)xx < (unsigned)WN)
                    v = *(const float4*)(inb + (size_t)xx * cbuf + ci0 + ci4);
                *(float4*)(&As[px][ci4]) = v;
            }
        }
#pragma unroll
        for (int dx = 0; dx < 3; ++dx) {
            int ci = tid >> 3, oc4 = (tid & 7) << 2;
            int t = s * 3 + dx;
            float4 wv = *(const float4*)(wt + (size_t)(t * cin + ci0 + ci) * wstride + n0 + oc4);
            *(float4*)(&Bs[dx][ci][oc4]) = wv;
        }
        __syncthreads();
#pragma unroll
        for (int dx = 0; dx < 3; ++dx) {
#pragma unroll 8
            for (int k = 0; k < 32; ++k) {
                float b0 = Bs[dx][k][tn], b1 = Bs[dx][k][tn + 1];
#pragma unroll
                for (int i = 0; i < 4; ++i) {
                    float a = As[tl + (i << 4) + dx][k];
                    acc[i][0] += a * b0;
                    acc[i][1] += a * b1;
                }
            }
        }
        __syncthreads();
    }
    if (PLANAR) {
#pragma unroll
        for (int j = 0; j < 2; ++j) {
            float* pp = part + ((size_t)((s * NB + b) * 64 + n0 + tn + j)) * LEN + y0 * WN + tl;
#pragma unroll
            for (int i = 0; i < 4; ++i) pp[i << 4] = acc[i][j];
        }
    } else {
#pragma unroll
        for (int i = 0; i < 4; ++i) {
            float* pp = part + (((size_t)(s * NB + b) * LEN) + y0 * WN + tl + (i << 4)) * 32 + tn;
            pp[0] = acc[i][0]; pp[1] = acc[i][1];
        }
    }
}

// epilogue: sum 3 dy-partials + bias + leakyrelu -> FN NHWC col block
__global__ void k_ep_nhwc(const float* __restrict__ part, const float* __restrict__ bias,
                          float* __restrict__ FN, int co0, float slope)
{
    int idx = blockIdx.x * 256 + threadIdx.x;
    int co = idx & 31, px = idx >> 5;
    const size_t S = (size_t)NB * LEN * 32;
    float v = part[idx] + part[S + idx] + part[2 * S + idx] + bias[co];
    v = v > 0.f ? v : v * slope;
    FN[(size_t)px * DM + co0 + co] = v;
}

// epilogue: sum 3 dy-partials + bias -> planar out (B,64,L)
__global__ void k_ep_pl(const float* __restrict__ part, const float* __restrict__ bias,
                        float* __restrict__ out)
{
    int idx = blockIdx.x * 256 + threadIdx.x;
    int oc = (idx >> 12) & 63;
    const size_t S = (size_t)NB * 64 * LEN;
    float v = part[idx] + part[S + idx] + part[2 * S + idx] + bias[oc];
    out[idx] = v;
}

// ---------------------------------------------------------------------------
// LayerNorm over 192 channels, NHWC in/out
__global__ void k_ln(const float* __restrict__ FN, const float* __restrict__ g,
                     const float* __restrict__ be, float* __restrict__ xn)
{
    int lane = threadIdx.x & 63;
    int pix  = (blockIdx.x << 2) + (threadIdx.x >> 6);
    const float* fp = FN + (size_t)pix * DM;
    float v0 = fp[lane];
    float v1 = fp[lane + 64];
    float v2 = fp[lane + 128];
    float s = v0 + v1 + v2, ss = v0 * v0 + v1 * v1 + v2 * v2;
#pragma unroll
    for (int off = 1; off < 64; off <<= 1) { s += __shfl_xor(s, off); ss += __shfl_xor(ss, off); }
    float mu = s * (1.f / 192.f);
    float var = ss * (1.f / 192.f) - mu * mu;
    float rstd = rsqrtf(var + 1e-5f);
    float* op = xn + (size_t)pix * DM;
    op[lane]       = (v0 - mu) * rstd * g[lane]       + be[lane];
    op[lane + 64]  = (v1 - mu) * rstd * g[lane + 64]  + be[lane + 64];
    op[lane + 128] = (v2 - mu) * rstd * g[lane + 128] + be[lane + 128];
}

// ---------------------------------------------------------------------------
// bf16 MFMA GEMM core: stages A (64 x 64k) and W (64 x 64k) as bf16 in LDS,
// 4 waves each compute a 32x32 subtile via 2x2 x mfma_f32_16x16x32_bf16.
// Returns accumulators; caller handles the store.
struct MfTile { facc a00, a01, a10, a11; int mb, nb, lr, lq; };

__device__ __forceinline__ MfTile mf_gemm_core(
    const float* __restrict__ A, int K, const float* __restrict__ Wt,
    int b, int l0, int n0, unsigned short (*Asb)[72], unsigned short (*Bsb)[72])
{
    int tid = threadIdx.x;
    MfTile t;
    t.a00 = (facc){0,0,0,0}; t.a01 = (facc){0,0,0,0};
    t.a10 = (facc){0,0,0,0}; t.a11 = (facc){0,0,0,0};
    int wv = tid >> 6, lane = tid & 63;
    t.mb = (wv & 1) << 5; t.nb = (wv >> 1) << 5;
    t.lr = lane & 15; t.lq = lane >> 4;

    for (int k0 = 0; k0 < K; k0 += 64) {
#pragma unroll
        for (int s = 0; s < 4; ++s) {
            int idx = (s << 8) + tid;
            int row = idx >> 4, c4 = (idx & 15) << 2;
            float4 av = *(const float4*)(A + ((size_t)b * LEN + l0 + row) * K + k0 + c4);
            ushort4 ua; ua.x = f2bf(av.x); ua.y = f2bf(av.y); ua.z = f2bf(av.z); ua.w = f2bf(av.w);
            *(ushort4*)(&Asb[row][c4]) = ua;
            float4 wvv = *(const float4*)(Wt + (size_t)(n0 + row) * K + k0 + c4);
            ushort4 ub; ub.x = f2bf(wvv.x); ub.y = f2bf(wvv.y); ub.z = f2bf(wvv.z); ub.w = f2bf(wvv.w);
            *(ushort4*)(&Bsb[row][c4]) = ub;
        }
        __syncthreads();
#pragma unroll
        for (int kk = 0; kk < 64; kk += 32) {
            bfrag a0 = *(const bfrag*)(&Asb[t.mb + t.lr][kk + t.lq * 8]);
            bfrag a1 = *(const bfrag*)(&Asb[t.mb + 16 + t.lr][kk + t.lq * 8]);
            bfrag b0 = *(const bfrag*)(&Bsb[t.nb + t.lr][kk + t.lq * 8]);
            bfrag b1 = *(const bfrag*)(&Bsb[t.nb + 16 + t.lr][kk + t.lq * 8]);
            t.a00 = __builtin_amdgcn_mfma_f32_16x16x32_bf16(a0, b0, t.a00, 0, 0, 0);
            t.a01 = __builtin_amdgcn_mfma_f32_16x16x32_bf16(a0, b1, t.a01, 0, 0, 0);
            t.a10 = __builtin_amdgcn_mfma_f32_16x16x32_bf16(a1, b0, t.a10, 0, 0, 0);
            t.a11 = __builtin_amdgcn_mfma_f32_16x16x32_bf16(a1, b1, t.a11, 0, 0, 0);
        }
        __syncthreads();
    }
    return t;
}

// store one 16x16 fragment (NHWC): rows l0+m, cols n0+n, optional residual
__device__ __forceinline__ void mf_store(
    facc v, float* __restrict__ Cp, const float* __restrict__ res,
    int b, int l0, int n0, int outC, int lr, int lq)
{
#pragma unroll
    for (int r = 0; r < 4; ++r) {
        int m = lq * 4 + r, n = lr;
        size_t o = ((size_t)b * LEN + l0 + m) * outC + n0 + n;
        float x = v[r];
        if (res) x += res[o];
        Cp[o] = x;
    }
}

// generic MFMA GEMM: A (B*L,K) x Wt(N,K) -> NHWC Cp (B*L,outC), opt residual
__global__ void __launch_bounds__(256) k_gemm_mf(
    const float* __restrict__ A, int K, const float* __restrict__ Wt,
    const float* __restrict__ res, float* __restrict__ Cp, int outC)
{
    __shared__ unsigned short Asb[64][72];
    __shared__ unsigned short Bsb[64][72];
    int b = blockIdx.z, l0 = blockIdx.x << 6, n0 = blockIdx.y << 6;
    MfTile t = mf_gemm_core(A, K, Wt, b, l0, n0, Asb, Bsb);
    mf_store(t.a00, Cp, res, b, l0 + t.mb,      n0 + t.nb,      outC, t.lr, t.lq);
    mf_store(t.a01, Cp, res, b, l0 + t.mb,      n0 + t.nb + 16, outC, t.lr, t.lq);
    mf_store(t.a10, Cp, res, b, l0 + t.mb + 16, n0 + t.nb,      outC, t.lr, t.lq);
    mf_store(t.a11, Cp, res, b, l0 + t.mb + 16, n0 + t.nb + 16, outC, t.lr, t.lq);
}

// fused in_proj MFMA GEMM: y<6 -> xp NHWC (XPN), y>=6 -> z NHWC (ZT)
__global__ void __launch_bounds__(256) k_gemm_ipmf(
    const float* __restrict__ A, const float* __restrict__ Wt,
    float* __restrict__ XPN, float* __restrict__ ZT)
{
    __shared__ unsigned short Asb[64][72];
    __shared__ unsigned short Bsb[64][72];
    int b = blockIdx.z, l0 = blockIdx.x << 6, n0 = blockIdx.y << 6;
    MfTile t = mf_gemm_core(A, DM, Wt, b, l0, n0, Asb, Bsb);
    float* out = (blockIdx.y < 6) ? XPN : ZT;
    int nc = (blockIdx.y < 6) ? n0 : n0 - DIM;
    mf_store(t.a00, out, nullptr, b, l0 + t.mb,      nc + t.nb,      DIM, t.lr, t.lq);
    mf_store(t.a01, out, nullptr, b, l0 + t.mb,      nc + t.nb + 16, DIM, t.lr, t.lq);
    mf_store(t.a10, out, nullptr, b, l0 + t.mb + 16, nc + t.nb,      DIM, t.lr, t.lq);
    mf_store(t.a11, out, nullptr, b, l0 + t.mb + 16, nc + t.nb + 16, DIM, t.lr, t.lq);
}

// ---------------------------------------------------------------------------
// depthwise conv3x3 + SiLU, NHWC in (XPN) -> NHWC out (unh)
__global__ void __launch_bounds__(256) k_dw(
    const float* __restrict__ xpn, const float* __restrict__ w,
    const float* __restrict__ bias, float* __restrict__ unh)
{
    int b = blockIdx.z, cg = blockIdx.y, r = blockIdx.x;
    int lane = threadIdx.x & 63, wv = threadIdx.x >> 6;
    int c = cg * 64 + lane;
    float wl[9];
#pragma unroll
    for (int t = 0; t < 9; ++t) wl[t] = w[c * 9 + t];
    float bv = bias[c];
    const float* base = xpn + (size_t)b * LEN * DIM + c;
    float* ob = unh + (size_t)b * LEN * DIM + c;
#pragma unroll 4
    for (int xi = 0; xi < 16; ++xi) {
        int x = wv * 16 + xi;
        float acc = bv;
#pragma unroll
        for (int dy = 0; dy < 3; ++dy) {
            int ry = r + dy - 1;
            if ((unsigned)ry >= (unsigned)HN) continue;
#pragma unroll
            for (int dx = 0; dx < 3; ++dx) {
                int xx = x + dx - 1;
                if ((unsigned)xx >= (unsigned)WN) continue;
                acc += base[(size_t)(ry * WN + xx) * DIM] * wl[dy * 3 + dx];
            }
        }
        acc = acc / (1.f + __expf(-acc));
        ob[(size_t)(r * WN + x) * DIM] = acc;
    }
}

// ---------------------------------------------------------------------------
// delta = softplus(dtb + CX[:, k*48+0..12] @ dtw[k]^T), pixel-order output
__global__ void __launch_bounds__(384) k_delta(
    const float* __restrict__ CX, const float* __restrict__ dtw,
    const float* __restrict__ dtb, float* __restrict__ dlt)
{
    __shared__ float cs[16][12];
    int b = blockIdx.z, k = blockIdx.y;
    int lp0 = blockIdx.x << 4;
    int tid = threadIdx.x;
    if (tid < 192) {
        int p = tid / 12, r = tid - p * 12;
        cs[p][r] = CX[((size_t)(b * LEN) + lp0 + p) * 192 + k * 48 + r];
    }
    __syncthreads();
    float wt[DTR];
    const float* wp = dtw + ((size_t)(k * DIM) + tid) * DTR;
#pragma unroll
    for (int r = 0; r < DTR; ++r) wt[r] = wp[r];
    float bv = dtb[k * DIM + tid];
    float* dbase = dlt + (((size_t)(b * LEN) + lp0) * KD + k) * DIM + tid;
#pragma unroll
    for (int p = 0; p < 16; ++p) {
        float s = bv;
#pragma unroll
        for (int r = 0; r < DTR; ++r) s += cs[p][r] * wt[r];
        s = (s > 20.f) ? s : __logf(1.f + __expf(s));
        dbase[(size_t)p * KD * DIM] = s;
    }
}

// ---------------------------------------------------------------------------
// chunked scan phase A. thread = d; 16 states in registers; geometric-A fast path.
__global__ void __launch_bounds__(384) k_scan_a(
    const float* __restrict__ unh, const float* __restrict__ CX,
    const float* __restrict__ alog, const float* __restrict__ dlt,
    float* __restrict__ hf, float* __restrict__ pA)
{
    __shared__ float bs[CHL * 16];
    int b = blockIdx.z, k = blockIdx.y, c = blockIdx.x;
    int d = threadIdx.x;
    for (int i = threadIdx.x; i < CHL * 16; i += 384) {
        int l = i >> 4, n = i & 15;
        int row = maprow(k, c * CHL + l);
        bs[i] = CX[((size_t)(b * LEN) + row) * 192 + k * 48 + 12 + n];
    }
    __syncthreads();

    float A[16], h[16];
    const float* ap = alog + ((size_t)(k * DIM + d)) * NST;
#pragma unroll
    for (int q = 0; q < 4; ++q) {
        float4 av = *(const float4*)(ap + q * 4);
        A[q * 4]     = -__expf(av.x); A[q * 4 + 1] = -__expf(av.y);
        A[q * 4 + 2] = -__expf(av.z); A[q * 4 + 3] = -__expf(av.w);
    }
    bool geo = true;
#pragma unroll
    for (int n = 1; n < 16; ++n)
        geo = geo && (fabsf(A[n] - (n + 1) * A[0]) <= 1e-4f * (n + 1) * fabsf(A[0]));
#pragma unroll
    for (int n = 0; n < 16; ++n) h[n] = 0.f;

    const float* ub = unh + (size_t)b * LEN * DIM + d;
    const float* db = dlt + ((size_t)(b * LEN) * KD + k) * DIM + d;
    size_t base = (((size_t)((b * KD + k) * NC + c)) * NST) * DIM + d;

    float dv0[4], uu0[4], dv1[4], uu1[4];
#pragma unroll
    for (int j = 0; j < 4; ++j) {
        int row = maprow(k, c * CHL + j);
        dv0[j] = db[(size_t)row * KD * DIM];
        uu0[j] = ub[(size_t)row * DIM];
    }
    if (geo) {
        float A0 = A[0];
        float p0 = 1.f;
        for (int l0 = 0; l0 < CHL; l0 += 4) {
            if (l0 + 4 < CHL) {
#pragma unroll
                for (int j = 0; j < 4; ++j) {
                    int row = maprow(k, c * CHL + l0 + 4 + j);
                    dv1[j] = db[(size_t)row * KD * DIM];
                    uu1[j] = ub[(size_t)row * DIM];
                }
            }
#pragma unroll
            for (int j = 0; j < 4; ++j) {
                float du = dv0[j] * uu0[j];
                const float* bl = bs + (l0 + j) * 16;
                float qv = __expf(dv0[j] * A0);
                float pw = qv;
                h[0] = qv * h[0] + du * bl[0];
#pragma unroll
                for (int n = 1; n < 16; ++n) { pw *= qv; h[n] = pw * h[n] + du * bl[n]; }
                p0 *= qv;
            }
#pragma unroll
            for (int j = 0; j < 4; ++j) { dv0[j] = dv1[j]; uu0[j] = uu1[j]; }
        }
        float pw = 1.f;
#pragma unroll
        for (int n = 0; n < 16; ++n) {
            pw *= p0;
            hf[base + (size_t)n * DIM] = h[n];
            pA[base + (size_t)n * DIM] = pw;
        }
    } else {
        float p[16];
#pragma unroll
        for (int n = 0; n < 16; ++n) p[n] = 1.f;
        for (int l0 = 0; l0 < CHL; l0 += 4) {
            if (l0 + 4 < CHL) {
#pragma unroll
                for (int j = 0; j < 4; ++j) {
                    int row = maprow(k, c * CHL + l0 + 4 + j);
                    dv1[j] = db[(size_t)row * KD * DIM];
                    uu1[j] = ub[(size_t)row * DIM];
                }
            }
#pragma unroll
            for (int j = 0; j < 4; ++j) {
                float du = dv0[j] * uu0[j];
                const float* bl = bs + (l0 + j) * 16;
#pragma unroll
                for (int n = 0; n < 16; ++n) {
                    float dA = __expf(dv0[j] * A[n]);
                    h[n] = dA * h[n] + du * bl[n];
                    p[n] *= dA;
                }
            }
#pragma unroll
            for (int j = 0; j < 4; ++j) { dv0[j] = dv1[j]; uu0[j] = uu1[j]; }
        }
#pragma unroll
        for (int n = 0; n < 16; ++n) {
            hf[base + (size_t)n * DIM] = h[n];
            pA[base + (size_t)n * DIM] = p[n];
        }
    }
}

// phase B: serial carry combine over chunks; hf[c] overwritten with carry-IN.
__global__ void k_scan_b(float* __restrict__ hf, const float* __restrict__ pA)
{
    int s = blockIdx.x * 256 + threadIdx.x;          // NB*KD*NST*DIM = 49152
    int bk = s / (NST * DIM);
    int r  = s - bk * (NST * DIM);
    size_t base = (size_t)bk * NC * NST * DIM + r;
    const size_t cs = (size_t)NST * DIM;
    float car = 0.f;
#pragma unroll 8
    for (int c = 0; c < NC; ++c) {
        float hfc = hf[base + c * cs], pc = pA[base + c * cs];
        hf[base + c * cs] = car;
        car = pc * car + hfc;
    }
}

// phase C: re-run chunk from carry-in; geometric-A fast path; y pixel-order.
__global__ void __launch_bounds__(384) k_scan_c(
    const float* __restrict__ unh, const float* __restrict__ CX,
    const float* __restrict__ alog, const float* __restrict__ hf,
    float* __restrict__ dlt)
{
    __shared__ float bs[CHL * 32];
    int b = blockIdx.z, k = blockIdx.y, c = blockIdx.x;
    int d = threadIdx.x;
    for (int i = threadIdx.x; i < CHL * 32; i += 384) {
        int l = i >> 5, n = i & 31;
        int row = maprow(k, c * CHL + l);
        bs[i] = CX[((size_t)(b * LEN) + row) * 192 + k * 48 + 12 + n];
    }
    __syncthreads();

    float A[16], h[16];
    const float* ap = alog + ((size_t)(k * DIM + d)) * NST;
#pragma unroll
    for (int q = 0; q < 4; ++q) {
        float4 av = *(const float4*)(ap + q * 4);
        A[q * 4]     = -__expf(av.x); A[q * 4 + 1] = -__expf(av.y);
        A[q * 4 + 2] = -__expf(av.z); A[q * 4 + 3] = -__expf(av.w);
    }
    bool geo = true;
#pragma unroll
    for (int n = 1; n < 16; ++n)
        geo = geo && (fabsf(A[n] - (n + 1) * A[0]) <= 1e-4f * (n + 1) * fabsf(A[0]));
    size_t base = (((size_t)((b * KD + k) * NC + c)) * NST) * DIM + d;
#pragma unroll
    for (int n = 0; n < 16; ++n) h[n] = hf[base + (size_t)n * DIM];

    const float* ub = unh + (size_t)b * LEN * DIM + d;
    float* db = dlt + ((size_t)(b * LEN) * KD + k) * DIM + d;

    int rows0[4], rows1[4];
    float dv0[4], uu0[4], dv1[4], uu1[4];
#pragma unroll
    for (int j = 0; j < 4; ++j) {
        rows0[j] = maprow(k, c * CHL + j);
        dv0[j] = db[(size_t)rows0[j] * KD * DIM];
        uu0[j] = ub[(size_t)rows0[j] * DIM];
    }
    if (geo) {
        float A0 = A[0];
        for (int l0 = 0; l0 < CHL; l0 += 4) {
            if (l0 + 4 < CHL) {
#pragma unroll
                for (int j = 0; j < 4; ++j) {
                    rows1[j] = maprow(k, c * CHL + l0 + 4 + j);
                    dv1[j] = db[(size_t)rows1[j] * KD * DIM];
                    uu1[j] = ub[(size_t)rows1[j] * DIM];
                }
            }
            float ys[4];
#pragma unroll
            for (int j = 0; j < 4; ++j) {
                const float* bl = bs + (l0 + j) * 32;
                float du = dv0[j] * uu0[j];
                float qv = __expf(dv0[j] * A0);
                float pw = qv;
                h[0] = qv * h[0] + du * bl[0];
                float y = h[0] * bl[16];
#pragma unroll
                for (int n = 1; n < 16; ++n) {
                    pw *= qv;
                    h[n] = pw * h[n] + du * bl[n];
                    y += h[n] * bl[16 + n];
                }
                ys[j] = y;
            }
#pragma unroll
            for (int j = 0; j < 4; ++j) db[(size_t)rows0[j] * KD * DIM] = ys[j];
#pragma unroll
            for (int j = 0; j < 4; ++j) { rows0[j] = rows1[j]; dv0[j] = dv1[j]; uu0[j] = uu1[j]; }
        }
    } else {
        for (int l0 = 0; l0 < CHL; l0 += 4) {
            if (l0 + 4 < CHL) {
#pragma unroll
                for (int j = 0; j < 4; ++j) {
                    rows1[j] = maprow(k, c * CHL + l0 + 4 + j);
                    dv1[j] = db[(size_t)rows1[j] * KD * DIM];
                    uu1[j] = ub[(size_t)rows1[j] * DIM];
                }
            }
            float ys[4];
#pragma unroll
            for (int j = 0; j < 4; ++j) {
                const float* bl = bs + (l0 + j) * 32;
                float du = dv0[j] * uu0[j];
                float y = 0.f;
#pragma unroll
                for (int n = 0; n < 16; ++n) {
                    float dA = __expf(dv0[j] * A[n]);
                    h[n] = dA * h[n] + du * bl[n];
                    y += h[n] * bl[16 + n];
                }
                ys[j] = y;
            }
#pragma unroll
            for (int j = 0; j < 4; ++j) db[(size_t)rows0[j] * KD * DIM] = ys[j];
#pragma unroll
            for (int j = 0; j < 4; ++j) { rows0[j] = rows1[j]; dv0[j] = dv1[j]; uu0[j] = uu1[j]; }
        }
    }
}

// ---------------------------------------------------------------------------
// merge 4 directions + D*u + out-LN + silu(z) gate -> yg NHWC (in-place over unh)
__global__ void k_merge(const float* __restrict__ y4, const float* __restrict__ unh,
                        const float* __restrict__ Ds, const float* __restrict__ ong,
                        const float* __restrict__ onb, const float* __restrict__ zt,
                        float* __restrict__ yg)
{
    int lane = threadIdx.x & 63;
    int pix = (blockIdx.x << 2) + (threadIdx.x >> 6);
    const float* yp = y4 + (size_t)pix * KD * DIM;
    const float* up = unh + (size_t)pix * DIM;
    float v[6]; float s = 0.f, ss = 0.f;
#pragma unroll
    for (int j = 0; j < 6; ++j) {
        int d = lane + (j << 6);
        float y = yp[d] + yp[DIM + d] + yp[2 * DIM + d] + yp[3 * DIM + d];
        float dsum = Ds[d] + Ds[DIM + d] + Ds[2 * DIM + d] + Ds[3 * DIM + d];
        y += dsum * up[d];
        v[j] = y; s += y; ss += y * y;
    }
#pragma unroll
    for (int off = 1; off < 64; off <<= 1) { s += __shfl_xor(s, off); ss += __shfl_xor(ss, off); }
    float mu = s * (1.f / 384.f);
    float var = ss * (1.f / 384.f) - mu * mu;
    float rstd = rsqrtf(var + 1e-5f);
    const float* zp = zt + (size_t)pix * DIM;
    float* op = yg + (size_t)pix * DIM;
#pragma unroll
    for (int j = 0; j < 6; ++j) {
        int d = lane + (j << 6);
        float zz = zp[d];
        float gate = zz / (1.f + __expf(-zz));
        op[d] = ((v[j] - mu) * rstd * ong[d] + onb[d]) * gate;
    }
}

// ---------------------------------------------------------------------------
extern "C" void kernel_launch(void* const* d_in, const int* in_sizes, int n_in,
                              void* d_out, int out_size, void* d_ws, size_t ws_size,
                              hipStream_t stream)
{
    const float* x    = (const float*)d_in[0];
    const float* c1w  = (const float*)d_in[1];  const float* c1b = (const float*)d_in[2];
    const float* c2w  = (const float*)d_in[3];  const float* c2b = (const float*)d_in[4];
    const float* c3w  = (const float*)d_in[5];  const float* c3b = (const float*)d_in[6];
    const float* c4w  = (const float*)d_in[7];  const float* c4b = (const float*)d_in[8];
    const float* c5w  = (const float*)d_in[9];  const float* c5b = (const float*)d_in[10];
    const float* ln1g = (const float*)d_in[11]; const float* ln1b= (const float*)d_in[12];
    const float* ipw  = (const float*)d_in[13];
    const float* dww  = (const float*)d_in[14]; const float* dwb = (const float*)d_in[15];
    const float* xpw  = (const float*)d_in[16];
    const float* dtw  = (const float*)d_in[17]; const float* dtb = (const float*)d_in[18];
    const float* alog = (const float*)d_in[19]; const float* dsv = (const float*)d_in[20];
    const float* ong  = (const float*)d_in[21]; const float* onb = (const float*)d_in[22];
    const float* opw  = (const float*)d_in[23];
    float* out = (float*)d_out;

    float* ws   = (float*)d_ws;
    float* FN   = ws;                   // (B*L,192) NHWC feature     1,572,864
    float* XN   = FN   + 1572864;       // PART-A / ln-out / CX / PART-C
    float* XPN  = XN   + 1572864;       // (B*L,384) xp NHWC; PA after dw
    float* ZT   = XPN  + 3145728;       // (B*L,384) z NHWC
    float* XCNH = ZT   + 3145728;       // (B*L,384) u NHWC; yg in-place
    float* DLT  = XCNH + 3145728;       // (B,L,4,384) delta->y; YN after merge
    float* HF   = DLT  + 12582912;      // carries (bk,c,n,d)         3,145,728
    float* WT14 = HF   + 3145728;       // transformed w c1..c4         129,024
    float* WT5  = WT14 + 129024;        // transformed w c5             110,592
    float* WX   = WT5  + 110592;        // padded x_proj_w (192,384)     73,728
    // total 28,612,096 floats = 109.1 MiB
    float* PA = XPN;                    // 3,145,728 = NB*KD*NC*NST*DIM exactly
    float* CX = XN;                     // 1,572,864 = NB*LEN*192 exactly
    float* PART = XN;                   // conv partials (stage A & C)
    float* YN = DLT;                    // out_proj output NHWC (B*L,192)

    // weight transforms  (wt layout: (t, ci, co) — r10 proven)
    k_wtr<<<dim3(72),  256, 0, stream>>>(c1w, WT14,          64, 32, 9 * 64 * 32);
    k_wtr<<<dim3(108), 256, 0, stream>>>(c2w, WT14 + 18432,  96, 32, 9 * 96 * 32);
    k_wtr<<<dim3(144), 256, 0, stream>>>(c3w, WT14 + 46080, 128, 32, 9 * 128 * 32);
    k_wtr<<<dim3(180), 256, 0, stream>>>(c4w, WT14 + 82944, 160, 32, 9 * 160 * 32);
    k_wtr<<<dim3(432), 256, 0, stream>>>(c5w, WT5,          192, 64, 9 * 192 * 64);
    k_wxp<<<dim3(288), 256, 0, stream>>>(xpw, WX);

    // stage A: dense conv block (implicit GEMM, halo-staged, f32)
    k_tr_in<<<dim3(HN, NB), 256, 0, stream>>>(x, FN);
    k_convg<0><<<dim3(64, 1, NB * 3), 256, 0, stream>>>(FN, DM, 64, WT14, 32, PART);
    k_ep_nhwc<<<dim3(1024), 256, 0, stream>>>(PART, c1b, FN, 64, 0.01f);
    k_convg<0><<<dim3(64, 1, NB * 3), 256, 0, stream>>>(FN, DM, 96, WT14 + 18432, 32, PART);
    k_ep_nhwc<<<dim3(1024), 256, 0, stream>>>(PART, c2b, FN, 96, 0.01f);
    k_convg<0><<<dim3(64, 1, NB * 3), 256, 0, stream>>>(FN, DM, 128, WT14 + 46080, 32, PART);
    k_ep_nhwc<<<dim3(1024), 256, 0, stream>>>(PART, c3b, FN, 128, 0.01f);
    k_convg<0><<<dim3(64, 1, NB * 3), 256, 0, stream>>>(FN, DM, 160, WT14 + 82944, 32, PART);
    k_ep_nhwc<<<dim3(1024), 256, 0, stream>>>(PART, c4b, FN, 160, 0.01f);

    // stage B: VSS block (MFMA bf16 GEMMs)
    k_ln<<<dim3(NB * LEN / 4), 256, 0, stream>>>(FN, ln1g, ln1b, XN);
    k_gemm_ipmf<<<dim3(LEN / 64, 12, NB), 256, 0, stream>>>(XN, ipw, XPN, ZT);
    k_dw<<<dim3(HN, DIM / 64, NB), 256, 0, stream>>>(XPN, dww, dwb, XCNH);
    k_gemm_mf<<<dim3(LEN / 64, 3, NB), 256, 0, stream>>>(XCNH, DIM, WX, nullptr, CX, 192);
    k_delta<<<dim3(LEN / 16, KD, NB), 384, 0, stream>>>(CX, dtw, dtb, DLT);
    k_scan_a<<<dim3(NC, KD, NB), 384, 0, stream>>>(XCNH, CX, alog, DLT, HF, PA);
    k_scan_b<<<dim3(NB * KD * NST * DIM / 256), 256, 0, stream>>>(HF, PA);
    k_scan_c<<<dim3(NC, KD, NB), 384, 0, stream>>>(XCNH, CX, alog, HF, DLT);
    k_merge<<<dim3(NB * LEN / 4), 256, 0, stream>>>(DLT, XCNH, dsv, ong, onb, ZT, XCNH);
    k_gemm_mf<<<dim3(LEN / 64, 3, NB), 256, 0, stream>>>(XCNH, DIM, opw, FN, YN, DM);

    // stage C: final conv (implicit GEMM, planar out, f32)
    k_convg<1><<<dim3(64, 2, NB * 3), 256, 0, stream>>>(YN, DM, 192, WT5, 64, PART);
    k_ep_pl<<<dim3(2048), 256, 0, stream>>>(PART, c5b, out);
}

// Round 14
// 297.078 us; speedup vs baseline: 1.7295x; 1.2251x over previous
//
#include <hip/hip_runtime.h>
#include <hip/hip_bf16.h>
#include <math.h>

// ---- problem constants ----
static constexpr int LEN = 4096;   // H*W
static constexpr int HN  = 64;     // H
static constexpr int WN  = 64;     // W
static constexpr int NB  = 2;      // batch
static constexpr int DM  = 192;    // d_model
static constexpr int DIM = 384;    // d_inner
static constexpr int NST = 16;     // n_state
static constexpr int DTR = 12;     // dt_rank
static constexpr int KD  = 4;      // directions
static constexpr int NC  = 64;     // scan chunks
static constexpr int CHL = LEN / NC; // 64 elements per chunk

typedef __attribute__((ext_vector_type(8))) short bfrag;
typedef __attribute__((ext_vector_type(4))) float facc;

__device__ __forceinline__ unsigned short f2bf(float x) {
    unsigned int u = __float_as_uint(x);
    return (unsigned short)((u + 0x7FFFu + ((u >> 16) & 1u)) >> 16);
}

// direction k seq-position -> pixel row index (uniform across a wave)
__device__ __forceinline__ int maprow(int k, int gl) {
    int g = (k & 2) ? (LEN - 1 - gl) : gl;
    return (k & 1) ? (((g & 63) << 6) | (g >> 6)) : g;
}

// ---------------------------------------------------------------------------
// weight transform: w (co,ci,3,3) -> wt (t, co, ci)   [ci contiguous, MFMA B]
__global__ void k_wtr(const float* __restrict__ w, float* __restrict__ wt,
                      int cin, int cout, int n)
{
    int idx = blockIdx.x * 256 + threadIdx.x;
    if (idx >= n) return;
    int ci = idx % cin; int r = idx / cin;
    int co = r % cout; int t = r / cout;
    wt[idx] = w[((size_t)(co * cin + ci)) * 9 + t];
}

// pad x_proj_w (4,44,384) -> WX (192,384), rows k*48+c (c<44), zero pad
__global__ void k_wxp(const float* __restrict__ xpw, float* __restrict__ WX)
{
    int idx = blockIdx.x * 256 + threadIdx.x;    // 192*384
    if (idx >= 192 * DIM) return;
    int row = idx / DIM, d = idx - row * DIM;
    int k = row / 48, c = row - k * 48;
    WX[idx] = (c < 44) ? xpw[((size_t)(k * 44 + c)) * DIM + d] : 0.f;
}

// ---------------------------------------------------------------------------
// x (B,64,L) planar -> FN NHWC cols [0,64)
__global__ void k_tr_in(const float* __restrict__ x, float* __restrict__ FN)
{
    __shared__ float t[64][65];
    int b = blockIdx.y, r = blockIdx.x;
    int tid = threadIdx.x;
#pragma unroll
    for (int i = 0; i < 16; ++i) {
        int idx = (i << 8) + tid;
        int c = idx >> 6, xc = idx & 63;
        t[c][xc] = x[((size_t)(b * 64 + c)) * LEN + r * WN + xc];
    }
    __syncthreads();
#pragma unroll
    for (int i = 0; i < 16; ++i) {
        int idx = (i << 8) + tid;
        int px = idx >> 6, c = idx & 63;
        FN[((size_t)(b * LEN + r * WN + px)) * DM + c] = t[c][px];
    }
}

// ---------------------------------------------------------------------------
// MFMA conv3x3, dy-split partials (NHWC, stride=cout). bf16 halo-staged A;
// wave = 32px x 16oc subtile; 3 dx taps via LDS row shifts.
__global__ void __launch_bounds__(256) k_convmf(
    const float* __restrict__ in, int cbuf, int cin, int cout,
    const float* __restrict__ wt2,
    float* __restrict__ part)
{
    __shared__ unsigned short Asb[66][40];
    __shared__ unsigned short Bsb[3][32][40];
    int zz = blockIdx.z;
    int b = zz / 3, s = zz % 3;
    int y0 = blockIdx.x;
    int n0 = blockIdx.y << 5;
    int tid = threadIdx.x;
    int wv = tid >> 6, lane = tid & 63;
    int mb  = (wv & 1) << 5;               // px block 0/32
    int nbw = (wv >> 1) << 4;              // oc block 0/16
    int lr = lane & 15, lq = lane >> 4;
    int y = y0 + s - 1;
    bool yok = (unsigned)y < (unsigned)HN;
    const float* inb = in + ((size_t)b * LEN + (size_t)y * WN) * cbuf;

    facc acc0 = (facc){0,0,0,0}, acc1 = (facc){0,0,0,0};

    for (int ci0 = 0; ci0 < cin; ci0 += 32) {
        // stage As[px][ci]: px in [0,66) -> x = px-1 (halo), bf16
#pragma unroll
        for (int it = 0; it < 3; ++it) {
            int fi = (it << 8) + tid;
            if (fi < 528) {                       // 66 rows x 8 quads
                int px = fi >> 3, c4 = (fi & 7) << 2;
                int xx = px - 1;
                float4 v = make_float4(0.f, 0.f, 0.f, 0.f);
                if (yok && (unsigned)xx < (unsigned)WN)
                    v = *(const float4*)(inb + (size_t)xx * cbuf + ci0 + c4);
                ushort4 u; u.x = f2bf(v.x); u.y = f2bf(v.y); u.z = f2bf(v.z); u.w = f2bf(v.w);
                *(ushort4*)(&Asb[px][c4]) = u;
            }
        }
        // stage Bs[dx][oc][ci]: 3 x 32 x 32 bf16 (wt2 is (t, co, ci))
#pragma unroll
        for (int it = 0; it < 3; ++it) {
            int fi = (it << 8) + tid;             // 768 quads
            int dx = fi >> 8; int rem = fi & 255;
            int oc = rem >> 3, c4 = (rem & 7) << 2;
            int t = s * 3 + dx;
            float4 v = *(const float4*)(wt2 + ((size_t)(t * cout + n0 + oc)) * cin + ci0 + c4);
            ushort4 u; u.x = f2bf(v.x); u.y = f2bf(v.y); u.z = f2bf(v.z); u.w = f2bf(v.w);
            *(ushort4*)(&Bsb[dx][oc][c4]) = u;
        }
        __syncthreads();
#pragma unroll
        for (int dx = 0; dx < 3; ++dx) {
            bfrag a0 = *(const bfrag*)(&Asb[mb + lr + dx][lq * 8]);
            bfrag a1 = *(const bfrag*)(&Asb[mb + 16 + lr + dx][lq * 8]);
            bfrag b0 = *(const bfrag*)(&Bsb[dx][nbw + lr][lq * 8]);
            acc0 = __builtin_amdgcn_mfma_f32_16x16x32_bf16(a0, b0, acc0, 0, 0, 0);
            acc1 = __builtin_amdgcn_mfma_f32_16x16x32_bf16(a1, b0, acc1, 0, 0, 0);
        }
        __syncthreads();
    }
    // store NHWC partials (s,b,L,cout): C frag row(px)=lq*4+r, col(oc)=lr
    float* pb = part + (((size_t)(s * NB + b) * LEN) + y0 * WN) * cout + n0 + nbw + lr;
#pragma unroll
    for (int r = 0; r < 4; ++r) {
        int px0 = mb + lq * 4 + r;
        pb[(size_t)px0 * cout] = acc0[r];
        pb[(size_t)(px0 + 16) * cout] = acc1[r];
    }
}

// epilogue: sum 3 dy-partials + bias + leakyrelu -> FN NHWC col block
__global__ void k_ep_nhwc(const float* __restrict__ part, const float* __restrict__ bias,
                          float* __restrict__ FN, int co0, float slope)
{
    int idx = blockIdx.x * 256 + threadIdx.x;
    int co = idx & 31, px = idx >> 5;
    const size_t S = (size_t)NB * LEN * 32;
    float v = part[idx] + part[S + idx] + part[2 * S + idx] + bias[co];
    v = v > 0.f ? v : v * slope;
    FN[(size_t)px * DM + co0 + co] = v;
}

// epilogue c5: partials (s,b,L,64) NHWC -> planar out (B,64,L) via LDS transpose
__global__ void k_ep_pl_tr(const float* __restrict__ part, const float* __restrict__ bias,
                           float* __restrict__ out)
{
    __shared__ float t[64][65];
    int b = blockIdx.y, l0 = blockIdx.x << 6;
    int tid = threadIdx.x;
    const size_t S = (size_t)NB * LEN * 64;
#pragma unroll
    for (int i = 0; i < 16; ++i) {
        int idx = (i << 8) + tid;
        int px = idx >> 6, oc = idx & 63;
        size_t o = ((size_t)b * LEN + l0 + px) * 64 + oc;
        t[px][oc] = part[o] + part[S + o] + part[2 * S + o] + bias[oc];
    }
    __syncthreads();
#pragma unroll
    for (int i = 0; i < 16; ++i) {
        int idx = (i << 8) + tid;
        int oc = idx >> 6, px = idx & 63;
        out[((size_t)(b * 64 + oc)) * LEN + l0 + px] = t[px][oc];
    }
}

// ---------------------------------------------------------------------------
// LayerNorm over 192 channels, NHWC in/out
__global__ void k_ln(const float* __restrict__ FN, const float* __restrict__ g,
                     const float* __restrict__ be, float* __restrict__ xn)
{
    int lane = threadIdx.x & 63;
    int pix  = (blockIdx.x << 2) + (threadIdx.x >> 6);
    const float* fp = FN + (size_t)pix * DM;
    float v0 = fp[lane];
    float v1 = fp[lane + 64];
    float v2 = fp[lane + 128];
    float s = v0 + v1 + v2, ss = v0 * v0 + v1 * v1 + v2 * v2;
#pragma unroll
    for (int off = 1; off < 64; off <<= 1) { s += __shfl_xor(s, off); ss += __shfl_xor(ss, off); }
    float mu = s * (1.f / 192.f);
    float var = ss * (1.f / 192.f) - mu * mu;
    float rstd = rsqrtf(var + 1e-5f);
    float* op = xn + (size_t)pix * DM;
    op[lane]       = (v0 - mu) * rstd * g[lane]       + be[lane];
    op[lane + 64]  = (v1 - mu) * rstd * g[lane + 64]  + be[lane + 64];
    op[lane + 128] = (v2 - mu) * rstd * g[lane + 128] + be[lane + 128];
}

// ---------------------------------------------------------------------------
// bf16 MFMA GEMM core (r13-proven)
struct MfTile { facc a00, a01, a10, a11; int mb, nb, lr, lq; };

__device__ __forceinline__ MfTile mf_gemm_core(
    const float* __restrict__ A, int K, const float* __restrict__ Wt,
    int b, int l0, int n0, unsigned short (*Asb)[72], unsigned short (*Bsb)[72])
{
    int tid = threadIdx.x;
    MfTile t;
    t.a00 = (facc){0,0,0,0}; t.a01 = (facc){0,0,0,0};
    t.a10 = (facc){0,0,0,0}; t.a11 = (facc){0,0,0,0};
    int wv = tid >> 6, lane = tid & 63;
    t.mb = (wv & 1) << 5; t.nb = (wv >> 1) << 5;
    t.lr = lane & 15; t.lq = lane >> 4;

    for (int k0 = 0; k0 < K; k0 += 64) {
#pragma unroll
        for (int s = 0; s < 4; ++s) {
            int idx = (s << 8) + tid;
            int row = idx >> 4, c4 = (idx & 15) << 2;
            float4 av = *(const float4*)(A + ((size_t)b * LEN + l0 + row) * K + k0 + c4);
            ushort4 ua; ua.x = f2bf(av.x); ua.y = f2bf(av.y); ua.z = f2bf(av.z); ua.w = f2bf(av.w);
            *(ushort4*)(&Asb[row][c4]) = ua;
            float4 wvv = *(const float4*)(Wt + (size_t)(n0 + row) * K + k0 + c4);
            ushort4 ub; ub.x = f2bf(wvv.x); ub.y = f2bf(wvv.y); ub.z = f2bf(wvv.z); ub.w = f2bf(wvv.w);
            *(ushort4*)(&Bsb[row][c4]) = ub;
        }
        __syncthreads();
#pragma unroll
        for (int kk = 0; kk < 64; kk += 32) {
            bfrag a0 = *(const bfrag*)(&Asb[t.mb + t.lr][kk + t.lq * 8]);
            bfrag a1 = *(const bfrag*)(&Asb[t.mb + 16 + t.lr][kk + t.lq * 8]);
            bfrag b0 = *(const bfrag*)(&Bsb[t.nb + t.lr][kk + t.lq * 8]);
            bfrag b1 = *(const bfrag*)(&Bsb[t.nb + 16 + t.lr][kk + t.lq * 8]);
            t.a00 = __builtin_amdgcn_mfma_f32_16x16x32_bf16(a0, b0, t.a00, 0, 0, 0);
            t.a01 = __builtin_amdgcn_mfma_f32_16x16x32_bf16(a0, b1, t.a01, 0, 0, 0);
            t.a10 = __builtin_amdgcn_mfma_f32_16x16x32_bf16(a1, b0, t.a10, 0, 0, 0);
            t.a11 = __builtin_amdgcn_mfma_f32_16x16x32_bf16(a1, b1, t.a11, 0, 0, 0);
        }
        __syncthreads();
    }
    return t;
}

__device__ __forceinline__ void mf_store(
    facc v, float* __restrict__ Cp, const float* __restrict__ res,
    int b, int l0, int n0, int outC, int lr, int lq)
{
#pragma unroll
    for (int r = 0; r < 4; ++r) {
        int m = lq * 4 + r, n = lr;
        size_t o = ((size_t)b * LEN + l0 + m) * outC + n0 + n;
        float x = v[r];
        if (res) x += res[o];
        Cp[o] = x;
    }
}

// generic MFMA GEMM: A (B*L,K) x Wt(N,K) -> NHWC Cp (B*L,outC), opt residual
__global__ void __launch_bounds__(256) k_gemm_mf(
    const float* __restrict__ A, int K, const float* __restrict__ Wt,
    const float* __restrict__ res, float* __restrict__ Cp, int outC)
{
    __shared__ unsigned short Asb[64][72];
    __shared__ unsigned short Bsb[64][72];
    int b = blockIdx.z, l0 = blockIdx.x << 6, n0 = blockIdx.y << 6;
    MfTile t = mf_gemm_core(A, K, Wt, b, l0, n0, Asb, Bsb);
    mf_store(t.a00, Cp, res, b, l0 + t.mb,      n0 + t.nb,      outC, t.lr, t.lq);
    mf_store(t.a01, Cp, res, b, l0 + t.mb,      n0 + t.nb + 16, outC, t.lr, t.lq);
    mf_store(t.a10, Cp, res, b, l0 + t.mb + 16, n0 + t.nb,      outC, t.lr, t.lq);
    mf_store(t.a11, Cp, res, b, l0 + t.mb + 16, n0 + t.nb + 16, outC, t.lr, t.lq);
}

// fused in_proj MFMA GEMM: y<6 -> xp NHWC (XPN), y>=6 -> z NHWC (ZT)
__global__ void __launch_bounds__(256) k_gemm_ipmf(
    const float* __restrict__ A, const float* __restrict__ Wt,
    float* __restrict__ XPN, float* __restrict__ ZT)
{
    __shared__ unsigned short Asb[64][72];
    __shared__ unsigned short Bsb[64][72];
    int b = blockIdx.z, l0 = blockIdx.x << 6, n0 = blockIdx.y << 6;
    MfTile t = mf_gemm_core(A, DM, Wt, b, l0, n0, Asb, Bsb);
    float* out = (blockIdx.y < 6) ? XPN : ZT;
    int nc = (blockIdx.y < 6) ? n0 : n0 - DIM;
    mf_store(t.a00, out, nullptr, b, l0 + t.mb,      nc + t.nb,      DIM, t.lr, t.lq);
    mf_store(t.a01, out, nullptr, b, l0 + t.mb,      nc + t.nb + 16, DIM, t.lr, t.lq);
    mf_store(t.a10, out, nullptr, b, l0 + t.mb + 16, nc + t.nb,      DIM, t.lr, t.lq);
    mf_store(t.a11, out, nullptr, b, l0 + t.mb + 16, nc + t.nb + 16, DIM, t.lr, t.lq);
}

// ---------------------------------------------------------------------------
// depthwise conv3x3 + SiLU, NHWC in (XPN) -> NHWC out (unh)
__global__ void __launch_bounds__(256) k_dw(
    const float* __restrict__ xpn, const float* __restrict__ w,
    const float* __restrict__ bias, float* __restrict__ unh)
{
    int b = blockIdx.z, cg = blockIdx.y, r = blockIdx.x;
    int lane = threadIdx.x & 63, wv = threadIdx.x >> 6;
    int c = cg * 64 + lane;
    float wl[9];
#pragma unroll
    for (int t = 0; t < 9; ++t) wl[t] = w[c * 9 + t];
    float bv = bias[c];
    const float* base = xpn + (size_t)b * LEN * DIM + c;
    float* ob = unh + (size_t)b * LEN * DIM + c;
#pragma unroll 4
    for (int xi = 0; xi < 16; ++xi) {
        int x = wv * 16 + xi;
        float acc = bv;
#pragma unroll
        for (int dy = 0; dy < 3; ++dy) {
            int ry = r + dy - 1;
            if ((unsigned)ry >= (unsigned)HN) continue;
#pragma unroll
            for (int dx = 0; dx < 3; ++dx) {
                int xx = x + dx - 1;
                if ((unsigned)xx >= (unsigned)WN) continue;
                acc += base[(size_t)(ry * WN + xx) * DIM] * wl[dy * 3 + dx];
            }
        }
        acc = acc / (1.f + __expf(-acc));
        ob[(size_t)(r * WN + x) * DIM] = acc;
    }
}

// ---------------------------------------------------------------------------
// delta = softplus(dtb + CX[:, k*48+0..12] @ dtw[k]^T), pixel-order output
__global__ void __launch_bounds__(384) k_delta(
    const float* __restrict__ CX, const float* __restrict__ dtw,
    const float* __restrict__ dtb, float* __restrict__ dlt)
{
    __shared__ float cs[16][12];
    int b = blockIdx.z, k = blockIdx.y;
    int lp0 = blockIdx.x << 4;
    int tid = threadIdx.x;
    if (tid < 192) {
        int p = tid / 12, r = tid - p * 12;
        cs[p][r] = CX[((size_t)(b * LEN) + lp0 + p) * 192 + k * 48 + r];
    }
    __syncthreads();
    float wt[DTR];
    const float* wp = dtw + ((size_t)(k * DIM) + tid) * DTR;
#pragma unroll
    for (int r = 0; r < DTR; ++r) wt[r] = wp[r];
    float bv = dtb[k * DIM + tid];
    float* dbase = dlt + (((size_t)(b * LEN) + lp0) * KD + k) * DIM + tid;
#pragma unroll
    for (int p = 0; p < 16; ++p) {
        float s = bv;
#pragma unroll
        for (int r = 0; r < DTR; ++r) s += cs[p][r] * wt[r];
        s = (s > 20.f) ? s : __logf(1.f + __expf(s));
        dbase[(size_t)p * KD * DIM] = s;
    }
}

// ---------------------------------------------------------------------------
// chunked scan phase A. thread = d; 16 states in registers; geometric-A fast path.
__global__ void __launch_bounds__(384) k_scan_a(
    const float* __restrict__ unh, const float* __restrict__ CX,
    const float* __restrict__ alog, const float* __restrict__ dlt,
    float* __restrict__ hf, float* __restrict__ pA)
{
    __shared__ float bs[CHL * 16];
    int b = blockIdx.z, k = blockIdx.y, c = blockIdx.x;
    int d = threadIdx.x;
    for (int i = threadIdx.x; i < CHL * 16; i += 384) {
        int l = i >> 4, n = i & 15;
        int row = maprow(k, c * CHL + l);
        bs[i] = CX[((size_t)(b * LEN) + row) * 192 + k * 48 + 12 + n];
    }
    __syncthreads();

    float A[16], h[16];
    const float* ap = alog + ((size_t)(k * DIM + d)) * NST;
#pragma unroll
    for (int q = 0; q < 4; ++q) {
        float4 av = *(const float4*)(ap + q * 4);
        A[q * 4]     = -__expf(av.x); A[q * 4 + 1] = -__expf(av.y);
        A[q * 4 + 2] = -__expf(av.z); A[q * 4 + 3] = -__expf(av.w);
    }
    bool geo = true;
#pragma unroll
    for (int n = 1; n < 16; ++n)
        geo = geo && (fabsf(A[n] - (n + 1) * A[0]) <= 1e-4f * (n + 1) * fabsf(A[0]));
#pragma unroll
    for (int n = 0; n < 16; ++n) h[n] = 0.f;

    const float* ub = unh + (size_t)b * LEN * DIM + d;
    const float* db = dlt + ((size_t)(b * LEN) * KD + k) * DIM + d;
    size_t base = (((size_t)((b * KD + k) * NC + c)) * NST) * DIM + d;

    float dv0[4], uu0[4], dv1[4], uu1[4];
#pragma unroll
    for (int j = 0; j < 4; ++j) {
        int row = maprow(k, c * CHL + j);
        dv0[j] = db[(size_t)row * KD * DIM];
        uu0[j] = ub[(size_t)row * DIM];
    }
    if (geo) {
        float A0 = A[0];
        float p0 = 1.f;
        for (int l0 = 0; l0 < CHL; l0 += 4) {
            if (l0 + 4 < CHL) {
#pragma unroll
                for (int j = 0; j < 4; ++j) {
                    int row = maprow(k, c * CHL + l0 + 4 + j);
                    dv1[j] = db[(size_t)row * KD * DIM];
                    uu1[j] = ub[(size_t)row * DIM];
                }
            }
#pragma unroll
            for (int j = 0; j < 4; ++j) {
                float du = dv0[j] * uu0[j];
                const float* bl = bs + (l0 + j) * 16;
                float qv = __expf(dv0[j] * A0);
                float pw = qv;
                h[0] = qv * h[0] + du * bl[0];
#pragma unroll
                for (int n = 1; n < 16; ++n) { pw *= qv; h[n] = pw * h[n] + du * bl[n]; }
                p0 *= qv;
            }
#pragma unroll
            for (int j = 0; j < 4; ++j) { dv0[j] = dv1[j]; uu0[j] = uu1[j]; }
        }
        float pw = 1.f;
#pragma unroll
        for (int n = 0; n < 16; ++n) {
            pw *= p0;
            hf[base + (size_t)n * DIM] = h[n];
            pA[base + (size_t)n * DIM] = pw;
        }
    } else {
        float p[16];
#pragma unroll
        for (int n = 0; n < 16; ++n) p[n] = 1.f;
        for (int l0 = 0; l0 < CHL; l0 += 4) {
            if (l0 + 4 < CHL) {
#pragma unroll
                for (int j = 0; j < 4; ++j) {
                    int row = maprow(k, c * CHL + l0 + 4 + j);
                    dv1[j] = db[(size_t)row * KD * DIM];
                    uu1[j] = ub[(size_t)row * DIM];
                }
            }
#pragma unroll
            for (int j = 0; j < 4; ++j) {
                float du = dv0[j] * uu0[j];
                const float* bl = bs + (l0 + j) * 16;
#pragma unroll
                for (int n = 0; n < 16; ++n) {
                    float dA = __expf(dv0[j] * A[n]);
                    h[n] = dA * h[n] + du * bl[n];
                    p[n] *= dA;
                }
            }
#pragma unroll
            for (int j = 0; j < 4; ++j) { dv0[j] = dv1[j]; uu0[j] = uu1[j]; }
        }
#pragma unroll
        for (int n = 0; n < 16; ++n) {
            hf[base + (size_t)n * DIM] = h[n];
            pA[base + (size_t)n * DIM] = p[n];
        }
    }
}

// phase B: serial carry combine over chunks; hf[c] overwritten with carry-IN.
__global__ void k_scan_b(float* __restrict__ hf, const float* __restrict__ pA)
{
    int s = blockIdx.x * 256 + threadIdx.x;          // NB*KD*NST*DIM = 49152
    int bk = s / (NST * DIM);
    int r  = s - bk * (NST * DIM);
    size_t base = (size_t)bk * NC * NST * DIM + r;
    const size_t cs = (size_t)NST * DIM;
    float car = 0.f;
#pragma unroll 8
    for (int c = 0; c < NC; ++c) {
        float hfc = hf[base + c * cs], pc = pA[base + c * cs];
        hf[base + c * cs] = car;
        car = pc * car + hfc;
    }
}

// phase C: re-run chunk from carry-in; geometric-A fast path; y pixel-order.
__global__ void __launch_bounds__(384) k_scan_c(
    const float* __restrict__ unh, const float* __restrict__ CX,
    const float* __restrict__ alog, const float* __restrict__ hf,
    float* __restrict__ dlt)
{
    __shared__ float bs[CHL * 32];
    int b = blockIdx.z, k = blockIdx.y, c = blockIdx.x;
    int d = threadIdx.x;
    for (int i = threadIdx.x; i < CHL * 32; i += 384) {
        int l = i >> 5, n = i & 31;
        int row = maprow(k, c * CHL + l);
        bs[i] = CX[((size_t)(b * LEN) + row) * 192 + k * 48 + 12 + n];
    }
    __syncthreads();

    float A[16], h[16];
    const float* ap = alog + ((size_t)(k * DIM + d)) * NST;
#pragma unroll
    for (int q = 0; q < 4; ++q) {
        float4 av = *(const float4*)(ap + q * 4);
        A[q * 4]     = -__expf(av.x); A[q * 4 + 1] = -__expf(av.y);
        A[q * 4 + 2] = -__expf(av.z); A[q * 4 + 3] = -__expf(av.w);
    }
    bool geo = true;
#pragma unroll
    for (int n = 1; n < 16; ++n)
        geo = geo && (fabsf(A[n] - (n + 1) * A[0]) <= 1e-4f * (n + 1) * fabsf(A[0]));
    size_t base = (((size_t)((b * KD + k) * NC + c)) * NST) * DIM + d;
#pragma unroll
    for (int n = 0; n < 16; ++n) h[n] = hf[base + (size_t)n * DIM];

    const float* ub = unh + (size_t)b * LEN * DIM + d;
    float* db = dlt + ((size_t)(b * LEN) * KD + k) * DIM + d;

    int rows0[4], rows1[4];
    float dv0[4], uu0[4], dv1[4], uu1[4];
#pragma unroll
    for (int j = 0; j < 4; ++j) {
        rows0[j] = maprow(k, c * CHL + j);
        dv0[j] = db[(size_t)rows0[j] * KD * DIM];
        uu0[j] = ub[(size_t)rows0[j] * DIM];
    }
    if (geo) {
        float A0 = A[0];
        for (int l0 = 0; l0 < CHL; l0 += 4) {
            if (l0 + 4 < CHL) {
#pragma unroll
                for (int j = 0; j < 4; ++j) {
                    rows1[j] = maprow(k, c * CHL + l0 + 4 + j);
                    dv1[j] = db[(size_t)rows1[j] * KD * DIM];
                    uu1[j] = ub[(size_t)rows1[j] * DIM];
                }
            }
            float ys[4];
#pragma unroll
            for (int j = 0; j < 4; ++j) {
                const float* bl = bs + (l0 + j) * 32;
                float du = dv0[j] * uu0[j];
                float qv = __expf(dv0[j] * A0);
                float pw = qv;
                h[0] = qv * h[0] + du * bl[0];
                float y = h[0] * bl[16];
#pragma unroll
                for (int n = 1; n < 16; ++n) {
                    pw *= qv;
                    h[n] = pw * h[n] + du * bl[n];
                    y += h[n] * bl[16 + n];
                }
                ys[j] = y;
            }
#pragma unroll
            for (int j = 0; j < 4; ++j) db[(size_t)rows0[j] * KD * DIM] = ys[j];
#pragma unroll
            for (int j = 0; j < 4; ++j) { rows0[j] = rows1[j]; dv0[j] = dv1[j]; uu0[j] = uu1[j]; }
        }
    } else {
        for (int l0 = 0; l0 < CHL; l0 += 4) {
            if (l0 + 4 < CHL) {
#pragma unroll
                for (int j = 0; j < 4; ++j) {
                    rows1[j] = maprow(k, c * CHL + l0 + 4 + j);
                    dv1[j] = db[(size_t)rows1[j] * KD * DIM];
                    uu1[j] = ub[(size_t)rows1[j] * DIM];
                }
            }
            float ys[4];
#pragma unroll
            for (int j = 0; j < 4; ++j) {
                const float* bl = bs + (l0 + j) * 32;
                float du = dv0[j] * uu0[j];
                float y = 0.f;
#pragma unroll
                for (int n = 0; n < 16; ++n) {
                    float dA = __expf(dv0[j] * A[n]);
                    h[n] = dA * h[n] + du * bl[n];
                    y += h[n] * bl[16 + n];
                }
                ys[j] = y;
            }
#pragma unroll
            for (int j = 0; j < 4; ++j) db[(size_t)rows0[j] * KD * DIM] = ys[j];
#pragma unroll
            for (int j = 0; j < 4; ++j) { rows0[j] = rows1[j]; dv0[j] = dv1[j]; uu0[j] = uu1[j]; }
        }
    }
}

// ---------------------------------------------------------------------------
// merge 4 directions + D*u + out-LN + silu(z) gate -> yg NHWC (in-place over unh)
__global__ void k_merge(const float* __restrict__ y4, const float* __restrict__ unh,
                        const float* __restrict__ Ds, const float* __restrict__ ong,
                        const float* __restrict__ onb, const float* __restrict__ zt,
                        float* __restrict__ yg)
{
    int lane = threadIdx.x & 63;
    int pix = (blockIdx.x << 2) + (threadIdx.x >> 6);
    const float* yp = y4 + (size_t)pix * KD * DIM;
    const float* up = unh + (size_t)pix * DIM;
    float v[6]; float s = 0.f, ss = 0.f;
#pragma unroll
    for (int j = 0; j < 6; ++j) {
        int d = lane + (j << 6);
        float y = yp[d] + yp[DIM + d] + yp[2 * DIM + d] + yp[3 * DIM + d];
        float dsum = Ds[d] + Ds[DIM + d] + Ds[2 * DIM + d] + Ds[3 * DIM + d];
        y += dsum * up[d];
        v[j] = y; s += y; ss += y * y;
    }
#pragma unroll
    for (int off = 1; off < 64; off <<= 1) { s += __shfl_xor(s, off); ss += __shfl_xor(ss, off); }
    float mu = s * (1.f / 384.f);
    float var = ss * (1.f / 384.f) - mu * mu;
    float rstd = rsqrtf(var + 1e-5f);
    const float* zp = zt + (size_t)pix * DIM;
    float* op = yg + (size_t)pix * DIM;
#pragma unroll
    for (int j = 0; j < 6; ++j) {
        int d = lane + (j << 6);
        float zz = zp[d];
        float gate = zz / (1.f + __expf(-zz));
        op[d] = ((v[j] - mu) * rstd * ong[d] + onb[d]) * gate;
    }
}

// ---------------------------------------------------------------------------
extern "C" void kernel_launch(void* const* d_in, const int* in_sizes, int n_in,
                              void* d_out, int out_size, void* d_ws, size_t ws_size,
                              hipStream_t stream)
{
    const float* x    = (const float*)d_in[0];
    const float* c1w  = (const float*)d_in[1];  const float* c1b = (const float*)d_in[2];
    const float* c2w  = (const float*)d_in[3];  const float* c2b = (const float*)d_in[4];
    const float* c3w  = (const float*)d_in[5];  const float* c3b = (const float*)d_in[6];
    const float* c4w  = (const float*)d_in[7];  const float* c4b = (const float*)d_in[8];
    const float* c5w  = (const float*)d_in[9];  const float* c5b = (const float*)d_in[10];
    const float* ln1g = (const float*)d_in[11]; const float* ln1b= (const float*)d_in[12];
    const float* ipw  = (const float*)d_in[13];
    const float* dww  = (const float*)d_in[14]; const float* dwb = (const float*)d_in[15];
    const float* xpw  = (const float*)d_in[16];
    const float* dtw  = (const float*)d_in[17]; const float* dtb = (const float*)d_in[18];
    const float* alog = (const float*)d_in[19]; const float* dsv = (const float*)d_in[20];
    const float* ong  = (const float*)d_in[21]; const float* onb = (const float*)d_in[22];
    const float* opw  = (const float*)d_in[23];
    float* out = (float*)d_out;

    float* ws   = (float*)d_ws;
    float* FN   = ws;                   // (B*L,192) NHWC feature     1,572,864
    float* XN   = FN   + 1572864;       // PART-A / ln-out / CX / PART-C
    float* XPN  = XN   + 1572864;       // (B*L,384) xp NHWC; PA after dw
    float* ZT   = XPN  + 3145728;       // (B*L,384) z NHWC
    float* XCNH = ZT   + 3145728;       // (B*L,384) u NHWC; yg in-place
    float* DLT  = XCNH + 3145728;       // (B,L,4,384) delta->y; YN after merge
    float* HF   = DLT  + 12582912;      // carries (bk,c,n,d)         3,145,728
    float* WT14 = HF   + 3145728;       // transformed w c1..c4         129,024
    float* WT5  = WT14 + 129024;        // transformed w c5             110,592
    float* WX   = WT5  + 110592;        // padded x_proj_w (192,384)     73,728
    // total 28,612,096 floats = 109.1 MiB
    float* PA = XPN;                    // 3,145,728 = NB*KD*NC*NST*DIM exactly
    float* CX = XN;                     // 1,572,864 = NB*LEN*192 exactly
    float* PART = XN;                   // conv partials (stage A & C; C needs 1,572,864)
    float* YN = DLT;                    // out_proj output NHWC (B*L,192)

    // weight transforms  (wt layout: (t, co, ci) for MFMA B operand)
    k_wtr<<<dim3(72),  256, 0, stream>>>(c1w, WT14,          64, 32, 9 * 64 * 32);
    k_wtr<<<dim3(108), 256, 0, stream>>>(c2w, WT14 + 18432,  96, 32, 9 * 96 * 32);
    k_wtr<<<dim3(144), 256, 0, stream>>>(c3w, WT14 + 46080, 128, 32, 9 * 128 * 32);
    k_wtr<<<dim3(180), 256, 0, stream>>>(c4w, WT14 + 82944, 160, 32, 9 * 160 * 32);
    k_wtr<<<dim3(432), 256, 0, stream>>>(c5w, WT5,          192, 64, 9 * 192 * 64);
    k_wxp<<<dim3(288), 256, 0, stream>>>(xpw, WX);

    // stage A: dense conv block (MFMA bf16, halo-staged, dy-split)
    k_tr_in<<<dim3(HN, NB), 256, 0, stream>>>(x, FN);
    k_convmf<<<dim3(64, 1, NB * 3), 256, 0, stream>>>(FN, DM, 64, 32, WT14, PART);
    k_ep_nhwc<<<dim3(1024), 256, 0, stream>>>(PART, c1b, FN, 64, 0.01f);
    k_convmf<<<dim3(64, 1, NB * 3), 256, 0, stream>>>(FN, DM, 96, 32, WT14 + 18432, PART);
    k_ep_nhwc<<<dim3(1024), 256, 0, stream>>>(PART, c2b, FN, 96, 0.01f);
    k_convmf<<<dim3(64, 1, NB * 3), 256, 0, stream>>>(FN, DM, 128, 32, WT14 + 46080, PART);
    k_ep_nhwc<<<dim3(1024), 256, 0, stream>>>(PART, c3b, FN, 128, 0.01f);
    k_convmf<<<dim3(64, 1, NB * 3), 256, 0, stream>>>(FN, DM, 160, 32, WT14 + 82944, PART);
    k_ep_nhwc<<<dim3(1024), 256, 0, stream>>>(PART, c4b, FN, 160, 0.01f);

    // stage B: VSS block (MFMA bf16 GEMMs)
    k_ln<<<dim3(NB * LEN / 4), 256, 0, stream>>>(FN, ln1g, ln1b, XN);
    k_gemm_ipmf<<<dim3(LEN / 64, 12, NB), 256, 0, stream>>>(XN, ipw, XPN, ZT);
    k_dw<<<dim3(HN, DIM / 64, NB), 256, 0, stream>>>(XPN, dww, dwb, XCNH);
    k_gemm_mf<<<dim3(LEN / 64, 3, NB), 256, 0, stream>>>(XCNH, DIM, WX, nullptr, CX, 192);
    k_delta<<<dim3(LEN / 16, KD, NB), 384, 0, stream>>>(CX, dtw, dtb, DLT);
    k_scan_a<<<dim3(NC, KD, NB), 384, 0, stream>>>(XCNH, CX, alog, DLT, HF, PA);
    k_scan_b<<<dim3(NB * KD * NST * DIM / 256), 256, 0, stream>>>(HF, PA);
    k_scan_c<<<dim3(NC, KD, NB), 384, 0, stream>>>(XCNH, CX, alog, HF, DLT);
    k_merge<<<dim3(NB * LEN / 4), 256, 0, stream>>>(DLT, XCNH, dsv, ong, onb, ZT, XCNH);
    k_gemm_mf<<<dim3(LEN / 64, 3, NB), 256, 0, stream>>>(XCNH, DIM, opw, FN, YN, DM);

    // stage C: final conv (MFMA bf16, NHWC partials + transpose epilogue)
    k_convmf<<<dim3(64, 2, NB * 3), 256, 0, stream>>>(YN, DM, 192, 64, WT5, PART);
    k_ep_pl_tr<<<dim3(64, NB), 256, 0, stream>>>(PART, c5b, out);
}